// Round 5
// baseline (1127.735 us; speedup 1.0000x reference)
//
#include <hip/hip_runtime.h>

#define N_NODES 100000
#define N_EDGES 1600000
#define N_PAD   100032   // 1563 * 64
#define NBLK    1563
#define NBUCK   391      // ceil(N_NODES / 256)

typedef __attribute__((ext_vector_type(4))) float f32x4;
typedef __attribute__((ext_vector_type(8))) short bf16x8;
typedef unsigned short ushort_t;
typedef unsigned int uint_t;

__device__ __forceinline__ ushort_t f2b(float f) {
    uint_t u = __float_as_uint(f);
    uint_t r = (u + 0x7FFFu + ((u >> 16) & 1u)) >> 16;   // RNE
    return (ushort_t)r;
}
__device__ __forceinline__ float b2f(ushort_t h) {
    return __uint_as_float(((uint_t)h) << 16);
}

// ================= CSR build =================

__global__ __launch_bounds__(256) void k_hist(
    const int* __restrict__ dst, int* __restrict__ deg, int nE)
{
    int e = blockIdx.x * blockDim.x + threadIdx.x;
    if (e < nE) atomicAdd(&deg[dst[e]], 1);
}

__global__ __launch_bounds__(256) void k_chunk_sum(
    const int* __restrict__ deg, int* __restrict__ bsum, int n)
{
    __shared__ int sred[4];
    int base = blockIdx.x * 1024;
    int s = 0;
    for (int i = threadIdx.x; i < 1024; i += 256) {
        int idx = base + i;
        s += (idx < n) ? deg[idx] : 0;
    }
    #pragma unroll
    for (int o = 32; o > 0; o >>= 1) s += __shfl_xor(s, o);
    if ((threadIdx.x & 63) == 0) sred[threadIdx.x >> 6] = s;
    __syncthreads();
    if (threadIdx.x == 0) bsum[blockIdx.x] = sred[0] + sred[1] + sred[2] + sred[3];
}

__global__ __launch_bounds__(128) void k_scan_bsum(int* bsum, int nb)
{
    int tid = threadIdx.x;
    int v = (tid < nb) ? bsum[tid] : 0;
    int lane = tid & 63, w = tid >> 6;
    int inc = v;
    #pragma unroll
    for (int o = 1; o < 64; o <<= 1) { int t = __shfl_up(inc, o); if (lane >= o) inc += t; }
    __shared__ int wsum[2];
    if (lane == 63) wsum[w] = inc;
    __syncthreads();
    int base = (w == 1) ? wsum[0] : 0;
    if (tid < nb) bsum[tid] = base + inc - v;
}

__global__ __launch_bounds__(256) void k_scan_final(
    const int* __restrict__ deg, const int* __restrict__ bsum,
    int* __restrict__ rowptr, int n)
{
    int tid = threadIdx.x;
    int idx0 = blockIdx.x * 1024 + tid * 4;
    int v[4]; int lsum = 0;
    #pragma unroll
    for (int j = 0; j < 4; ++j) { v[j] = (idx0 + j < n) ? deg[idx0 + j] : 0; lsum += v[j]; }
    int lane = tid & 63, w = tid >> 6;
    int inc = lsum;
    #pragma unroll
    for (int o = 1; o < 64; o <<= 1) { int t = __shfl_up(inc, o); if (lane >= o) inc += t; }
    __shared__ int wsum[4];
    if (lane == 63) wsum[w] = inc;
    __syncthreads();
    int wbase = 0;
    #pragma unroll
    for (int i = 0; i < 4; ++i) if (i < w) wbase += wsum[i];
    int excl = bsum[blockIdx.x] + wbase + inc - lsum;
    #pragma unroll
    for (int j = 0; j < 4; ++j) {
        if (idx0 + j < n) rowptr[idx0 + j] = excl;
        excl += v[j];
    }
}
// After k_scan_final: rowptr[i] = start offset of node i.

// bucket bases: bstart[b] = pcnt[b] = rowptr[b*256]
__global__ __launch_bounds__(256) void k_pcnt_init(
    const int* __restrict__ rowptr, int* __restrict__ pcnt, int* __restrict__ bstart)
{
    int b = blockIdx.x * 256 + threadIdx.x;
    if (b < NBUCK) { int v = rowptr[b << 8]; pcnt[b] = v; bstart[b] = v; }
}

// phase 1: bin edges by dst>>8 into ebuf (packed: local_dst<<24 | src)
__global__ __launch_bounds__(256) void k_bucket(
    const int* __restrict__ src, const int* __restrict__ dst,
    int* __restrict__ pcnt, uint_t* __restrict__ ebuf, int nE)
{
    int e = blockIdx.x * 256 + threadIdx.x;
    if (e >= nE) return;
    int d = dst[e];
    int pos = atomicAdd(&pcnt[d >> 8], 1);
    ebuf[pos] = ((uint_t)(d & 255) << 24) | (uint_t)src[e];
}

// phase 2: block per bucket; L2-local scatter into csr.
// atomicAdd shifts rowptr[i] -> end offset of node i.
__global__ __launch_bounds__(256) void k_scatter2(
    const uint_t* __restrict__ ebuf, const int* __restrict__ bstart,
    const int* __restrict__ pcnt, int* __restrict__ rowptr, int* __restrict__ csr)
{
    int b = blockIdx.x;
    int beg = bstart[b], end = pcnt[b];
    int nbase = b << 8;
    for (int i = beg + threadIdx.x; i < end; i += 256) {
        uint_t p = ebuf[i];
        int d = nbase + (int)(p >> 24);
        int pos = atomicAdd(&rowptr[d], 1);
        csr[pos] = (int)(p & 0xFFFFFFu);
    }
}
// After k_scatter2: node i's neighbors are csr[(i?rowptr[i-1]:0) .. rowptr[i])

// ================= weight prep: bf16 transpose W^T[F][K] =================

__global__ __launch_bounds__(256) void k_prep_w(
    const float* __restrict__ W2l, const float* __restrict__ W2r,
    const float* __restrict__ W3l, const float* __restrict__ W3r,
    ushort_t* __restrict__ wt2l, ushort_t* __restrict__ wt2r,
    ushort_t* __restrict__ wt3l, ushort_t* __restrict__ wt3r)
{
    int id = blockIdx.x * 256 + threadIdx.x;
    if (id < 16384)      { int j = id;         int f = j >> 7, k = j & 127; wt2l[j] = f2b(W2l[k*128 + f]); }
    else if (id < 32768) { int j = id - 16384; int f = j >> 7, k = j & 127; wt2r[j] = f2b(W2r[k*128 + f]); }
    else if (id < 40960) { int j = id - 32768; int f = j >> 7, k = j & 127; wt3l[j] = f2b(W3l[k*64 + f]); }
    else if (id < 49152) { int j = id - 40960; int f = j >> 7, k = j & 127; wt3r[j] = f2b(W3r[k*64 + f]); }
}

// ================= layer 1 (fused z-gather + MLP), wave per node, bf16 out =================

__global__ __launch_bounds__(256) void k_l1(
    const int* __restrict__ rowptr, const int* __restrict__ csr,
    const float* __restrict__ z,
    const float* __restrict__ W1l, const float* __restrict__ W1r,
    const float* __restrict__ b1, ushort_t* __restrict__ h1b, int n)
{
    int wid  = (blockIdx.x * 256 + threadIdx.x) >> 6;
    int lane = threadIdx.x & 63;
    if (wid >= n) return;
    int beg = wid ? rowptr[wid - 1] : 0;
    int end = rowptr[wid];
    float a0 = 0, a1 = 0, a2 = 0;
    for (int e = beg + lane; e < end; e += 64) {
        int s = csr[e];
        a0 += z[s * 3 + 0]; a1 += z[s * 3 + 1]; a2 += z[s * 3 + 2];
    }
    #pragma unroll
    for (int o = 32; o > 0; o >>= 1) {
        a0 += __shfl_xor(a0, o); a1 += __shfl_xor(a1, o); a2 += __shfl_xor(a2, o);
    }
    float iv = 1.0f / fmaxf((float)(end - beg), 1.0f);
    float m0 = a0 * iv, m1 = a1 * iv, m2 = a2 * iv;
    float z0 = z[wid * 3 + 0], z1 = z[wid * 3 + 1], z2 = z[wid * 3 + 2];
    int f0 = lane * 2;
    float2 bl  = *(const float2*)(b1 + f0);
    float2 l0 = *(const float2*)(W1l + 0*128 + f0);
    float2 l1 = *(const float2*)(W1l + 1*128 + f0);
    float2 l2 = *(const float2*)(W1l + 2*128 + f0);
    float2 r0 = *(const float2*)(W1r + 0*128 + f0);
    float2 r1 = *(const float2*)(W1r + 1*128 + f0);
    float2 r2 = *(const float2*)(W1r + 2*128 + f0);
    float v0 = bl.x + m0*l0.x + m1*l1.x + m2*l2.x + z0*r0.x + z1*r1.x + z2*r2.x;
    float v1 = bl.y + m0*l0.y + m1*l1.y + m2*l2.y + z0*r0.y + z1*r1.y + z2*r2.y;
    v0 = fmaxf(v0, 0.0f); v1 = fmaxf(v1, 0.0f);
    uint_t u = (uint_t)f2b(v0) | ((uint_t)f2b(v1) << 16);
    *(uint_t*)(h1b + (size_t)wid * 128 + f0) = u;
}

// ================= gathers (bf16 in), atomic-free =================

// F=128: wave per node, lane handles feats 2*lane, 2*lane+1; bf16 out
__global__ __launch_bounds__(256) void k_gather128(
    const int* __restrict__ rowptr, const int* __restrict__ csr,
    const ushort_t* __restrict__ x, ushort_t* __restrict__ out, int n)
{
    int wid  = (blockIdx.x * 256 + threadIdx.x) >> 6;
    int lane = threadIdx.x & 63;
    if (wid >= n) return;
    int beg = wid ? rowptr[wid - 1] : 0;
    int end = rowptr[wid];
    float a0 = 0.f, a1 = 0.f;
    for (int eb = beg; eb < end; eb += 64) {
        int cnt = min(64, end - eb);
        int my = (lane < cnt) ? csr[eb + lane] : 0;
        for (int j = 0; j < cnt; ++j) {
            int s = __shfl(my, j);
            uint_t v = *(const uint_t*)(x + (size_t)s * 128 + lane * 2);
            a0 += b2f((ushort_t)(v & 0xffffu));
            a1 += b2f((ushort_t)(v >> 16));
        }
    }
    float iv = 1.0f / fmaxf((float)(end - beg), 1.0f);
    uint_t u = (uint_t)f2b(a0 * iv) | ((uint_t)f2b(a1 * iv) << 16);
    *(uint_t*)(out + (size_t)wid * 128 + lane * 2) = u;
}

// F=64: half-wave per node, f32 out (consumed as post-GEMM addend)
__global__ __launch_bounds__(256) void k_gather64(
    const int* __restrict__ rowptr, const int* __restrict__ csr,
    const ushort_t* __restrict__ x, float* __restrict__ out, int n)
{
    int w    = (blockIdx.x * 256 + threadIdx.x) >> 6;
    int lane = threadIdx.x & 63;
    int sub  = lane >> 5, sl = lane & 31;
    int node = w * 2 + sub;
    if (node >= n) return;
    int beg = node ? rowptr[node - 1] : 0;
    int end = rowptr[node];
    float a0 = 0.f, a1 = 0.f;
    for (int eb = beg; eb < end; eb += 32) {
        int cnt = min(32, end - eb);
        int my = (sl < cnt) ? csr[eb + sl] : 0;
        for (int j = 0; j < cnt; ++j) {
            int s = __shfl(my, sub * 32 + j);
            uint_t v = *(const uint_t*)(x + (size_t)s * 64 + sl * 2);
            a0 += b2f((ushort_t)(v & 0xffffu));
            a1 += b2f((ushort_t)(v >> 16));
        }
    }
    float iv = 1.0f / fmaxf((float)(end - beg), 1.0f);
    float2 r; r.x = a0 * iv; r.y = a1 * iv;
    *(float2*)(out + (size_t)node * 64 + sl * 2) = r;
}

// ================= MFMA node GEMM =================
// out[i][f] = op( X1[i][:]@W1[:,f] (+ X2[i][:]@W2[:,f]) (+ pre[i][f]) (+ bias[f]) )
// X: [N_PAD][128] bf16 row-major. Wt: [F][128] bf16 (W transposed). 64 nodes/block, 4 waves.
template<int F, bool DUAL, bool ADDPRE, bool BIAS, bool RELU, bool OUTBF>
__global__ __launch_bounds__(256) void k_mfma(
    const ushort_t* __restrict__ X1, const ushort_t* __restrict__ Wt1,
    const ushort_t* __restrict__ X2, const ushort_t* __restrict__ Wt2,
    const float* __restrict__ pre, const float* __restrict__ bias,
    void* __restrict__ outv)
{
    constexpr int NB = F / 16;
    __shared__ short sX[(DUAL ? 2 : 1) * 64 * 128];
    const int tid  = threadIdx.x;
    const int wv   = tid >> 6, lane = tid & 63;
    const int hi   = lane >> 4, lo = lane & 15;
    const int base = blockIdx.x * 64;

    // stage X tiles: [64 rows][16 chunks of 16B], XOR-swizzled (c ^= row&7) -> 2-way-free ds_read
    #pragma unroll
    for (int m = 0; m < (DUAL ? 2 : 1); ++m) {
        const float4* gv = reinterpret_cast<const float4*>((m ? X2 : X1) + (size_t)base * 128);
        short* sb = &sX[m * 64 * 128];
        #pragma unroll
        for (int it = 0; it < 4; ++it) {
            int o = it * 256 + tid;
            int row = o >> 4, c = o & 15;
            float4 v = gv[row * 16 + c];
            *reinterpret_cast<float4*>(&sb[(row * 16 + (c ^ (row & 7))) * 8]) = v;
        }
    }
    __syncthreads();

    f32x4 acc[NB];
    #pragma unroll
    for (int b = 0; b < NB; ++b) acc[b] = (f32x4){0.f, 0.f, 0.f, 0.f};

    const int row = wv * 16 + lo;   // A-frag row within tile
    #pragma unroll
    for (int kk = 0; kk < 4; ++kk) {
        int sw = (kk * 4 + hi) ^ (row & 7);
        bf16x8 a1 = *reinterpret_cast<const bf16x8*>(&sX[(row * 16 + sw) * 8]);
        bf16x8 a2;
        if constexpr (DUAL)
            a2 = *reinterpret_cast<const bf16x8*>(&sX[64 * 128 + (row * 16 + sw) * 8]);
        #pragma unroll
        for (int b = 0; b < NB; ++b) {
            bf16x8 w1 = *reinterpret_cast<const bf16x8*>(Wt1 + (size_t)(b * 16 + lo) * 128 + kk * 32 + hi * 8);
            acc[b] = __builtin_amdgcn_mfma_f32_16x16x32_bf16(a1, w1, acc[b], 0, 0, 0);
            if constexpr (DUAL) {
                bf16x8 w2 = *reinterpret_cast<const bf16x8*>(Wt2 + (size_t)(b * 16 + lo) * 128 + kk * 32 + hi * 8);
                acc[b] = __builtin_amdgcn_mfma_f32_16x16x32_bf16(a2, w2, acc[b], 0, 0, 0);
            }
        }
    }

    // C/D layout: col = lane&15, row = (lane>>4)*4 + reg  [m89-verified]
    #pragma unroll
    for (int b = 0; b < NB; ++b) {
        #pragma unroll
        for (int r = 0; r < 4; ++r) {
            int node = base + wv * 16 + hi * 4 + r;
            int f    = b * 16 + lo;
            float v  = acc[b][r];
            if constexpr (ADDPRE) v += pre[(size_t)node * F + f];
            if constexpr (BIAS)   v += bias[f];
            if constexpr (RELU)   v = fmaxf(v, 0.0f);
            if constexpr (OUTBF)  ((ushort_t*)outv)[(size_t)node * F + f] = f2b(v);
            else                  ((float*)outv)[(size_t)node * F + f] = v;
        }
    }
}

// ================= output layer (f32 vector; K=64, F=40) =================

__global__ __launch_bounds__(256) void k_out(
    const float* __restrict__ h3, const float* __restrict__ W4,
    const float* __restrict__ b4, float* __restrict__ out, int n)
{
    int t = blockIdx.x * blockDim.x + threadIdx.x;
    int i = t / 40, f = t % 40;
    if (i >= n) return;
    float acc = b4[f];
    #pragma unroll
    for (int k = 0; k < 64; ++k) acc += h3[(size_t)i * 64 + k] * W4[k * 40 + f];
    out[t] = acc;
}

// ================= launch =================

extern "C" void kernel_launch(void* const* d_in, const int* in_sizes, int n_in,
                              void* d_out, int out_size, void* d_ws, size_t ws_size,
                              hipStream_t stream)
{
    const float* z   = (const float*)d_in[0];
    const int*   ei  = (const int*)d_in[1];
    const int*   src = ei;
    const int*   dst = ei + N_EDGES;
    const float* W1l = (const float*)d_in[2];
    const float* W1r = (const float*)d_in[3];
    const float* b1  = (const float*)d_in[4];
    const float* W2l = (const float*)d_in[5];
    const float* W2r = (const float*)d_in[6];
    const float* b2  = (const float*)d_in[7];
    const float* W3l = (const float*)d_in[8];
    const float* W3r = (const float*)d_in[9];
    const float* b3  = (const float*)d_in[10];
    const float* W4  = (const float*)d_in[11];
    const float* b4  = (const float*)d_in[12];
    float* out = (float*)d_out;

    // ---- workspace layout (all node arrays padded to N_PAD rows) ----
    ushort_t* h1b  = (ushort_t*)d_ws;                      // N_PAD*128 bf16
    ushort_t* aggb = h1b  + (size_t)N_PAD * 128;           // N_PAD*128 bf16
    ushort_t* h2b  = aggb + (size_t)N_PAD * 128;           // N_PAD*128 bf16
    ushort_t* t3b  = h2b  + (size_t)N_PAD * 128;           // N_PAD*64  bf16
    float* agg64   = (float*)(t3b + (size_t)N_PAD * 64);   // N_PAD*64  f32
    float* h3      = agg64 + (size_t)N_PAD * 64;           // N_PAD*64  f32
    int* rowptr    = (int*)(h3 + (size_t)N_PAD * 64);      // N ints
    int* csr       = rowptr + N_NODES;                     // E ints
    uint_t* ebuf   = (uint_t*)(csr + N_EDGES);             // E uints
    int* pcnt      = (int*)(ebuf + N_EDGES);               // NBUCK ints
    int* bstart    = pcnt + NBUCK;                         // NBUCK ints
    ushort_t* wt2l = (ushort_t*)(bstart + NBUCK);          // 128*128
    ushort_t* wt2r = wt2l + 128 * 128;
    ushort_t* wt3l = wt2r + 128 * 128;                     // 64*128
    ushort_t* wt3r = wt3l + 64 * 128;
    // deg/bsum alias h2b during CSR build (h2b written later)
    int* deg  = (int*)h2b;
    int* bsum = deg + N_NODES;

    const int NB = (N_NODES + 1023) / 1024;                // 98

    // ---- CSR build (bucketed two-phase scatter) ----
    hipMemsetAsync(deg, 0, N_NODES * sizeof(int), stream);
    k_hist      <<<(N_EDGES + 255) / 256, 256, 0, stream>>>(dst, deg, N_EDGES);
    k_chunk_sum <<<NB, 256, 0, stream>>>(deg, bsum, N_NODES);
    k_scan_bsum <<<1, 128, 0, stream>>>(bsum, NB);
    k_scan_final<<<NB, 256, 0, stream>>>(deg, bsum, rowptr, N_NODES);
    k_pcnt_init <<<2, 256, 0, stream>>>(rowptr, pcnt, bstart);
    k_bucket    <<<(N_EDGES + 255) / 256, 256, 0, stream>>>(src, dst, pcnt, ebuf, N_EDGES);
    k_scatter2  <<<NBUCK, 256, 0, stream>>>(ebuf, bstart, pcnt, rowptr, csr);

    // ---- weight prep (independent) ----
    k_prep_w<<<192, 256, 0, stream>>>(W2l, W2r, W3l, W3r, wt2l, wt2r, wt3l, wt3r);

    // ---- layer 1 ----
    k_l1<<<(N_NODES * 64 + 255) / 256, 256, 0, stream>>>(rowptr, csr, z, W1l, W1r, b1, h1b, N_NODES);

    // ---- layer 2 ----
    k_gather128<<<(N_NODES * 64 + 255) / 256, 256, 0, stream>>>(rowptr, csr, h1b, aggb, N_NODES);
    k_mfma<128, true,  false, true,  true,  true ><<<NBLK, 256, 0, stream>>>(
        aggb, wt2l, h1b, wt2r, nullptr, b2, h2b);

    // ---- layer 3 (pre-transform t3 = h2 @ W3l; mean is linear) ----
    k_mfma<64,  false, false, false, false, true ><<<NBLK, 256, 0, stream>>>(
        h2b, wt3l, nullptr, nullptr, nullptr, nullptr, t3b);
    k_gather64<<<((N_NODES + 1) / 2 * 64 + 255) / 256, 256, 0, stream>>>(rowptr, csr, t3b, agg64, N_NODES);
    k_mfma<64,  false, true,  true,  true,  false><<<NBLK, 256, 0, stream>>>(
        h2b, wt3r, nullptr, nullptr, agg64, b3, h3);

    // ---- output ----
    k_out<<<((size_t)N_NODES * 40 + 255) / 256, 256, 0, stream>>>(h3, W4, b4, out, N_NODES);
}

// Round 7
// 543.694 us; speedup vs baseline: 2.0742x; 2.0742x over previous
//
#include <hip/hip_runtime.h>

#define N_NODES 100000
#define N_EDGES 1600000
#define N_PAD   100032   // 1563 * 64
#define NBLK    1563
#define NBUCK   391      // ceil(N_NODES / 256), 256 nodes per bucket

typedef __attribute__((ext_vector_type(4))) float f32x4;
typedef __attribute__((ext_vector_type(8))) short bf16x8;
typedef unsigned short ushort_t;
typedef unsigned int uint_t;

__device__ __forceinline__ ushort_t f2b(float f) {
    uint_t u = __float_as_uint(f);
    uint_t r = (u + 0x7FFFu + ((u >> 16) & 1u)) >> 16;   // RNE
    return (ushort_t)r;
}
__device__ __forceinline__ float b2f(ushort_t h) {
    return __uint_as_float(((uint_t)h) << 16);
}

// ================= CSR build (bucketed, LDS-histogram) =================

// bucket sizes via per-block LDS histogram (391 global atomics/block, not 1/edge)
__global__ __launch_bounds__(256) void k_bcount(
    const int* __restrict__ dst, int* __restrict__ bsize, int nE)
{
    __shared__ int cnt[NBUCK];
    for (int i = threadIdx.x; i < NBUCK; i += 256) cnt[i] = 0;
    __syncthreads();
    int base = blockIdx.x * 1024;
    #pragma unroll
    for (int it = 0; it < 4; ++it) {
        int e = base + it * 256 + threadIdx.x;
        if (e < nE) atomicAdd(&cnt[dst[e] >> 8], 1);
    }
    __syncthreads();
    for (int i = threadIdx.x; i < NBUCK; i += 256)
        if (cnt[i]) atomicAdd(&bsize[i], cnt[i]);
}

// single wave: exclusive scan of bsize -> bstart, and init running cursors pcur
__global__ __launch_bounds__(64) void k_bscan(
    const int* __restrict__ bsize, int* __restrict__ bstart, int* __restrict__ pcur)
{
    int lane = threadIdx.x;
    int run = 0;
    for (int base = 0; base < NBUCK; base += 64) {
        int i = base + lane;
        int v = (i < NBUCK) ? bsize[i] : 0;
        int incl = v;
        #pragma unroll
        for (int o = 1; o < 64; o <<= 1) { int t = __shfl_up(incl, o); if (lane >= o) incl += t; }
        if (i < NBUCK) { int ex = run + incl - v; bstart[i] = ex; pcur[i] = ex; }
        run += __shfl(incl, 63);
    }
}

// phase 1: bin edges into ebuf (packed: local_dst<<24 | src), per-block LDS hist
// + one range-reservation atomic per bucket per block.
__global__ __launch_bounds__(256) void k_bucket(
    const int* __restrict__ src, const int* __restrict__ dst,
    int* __restrict__ pcur, uint_t* __restrict__ ebuf, int nE)
{
    __shared__ int cnt[NBUCK];
    __shared__ int rbase[NBUCK];
    for (int i = threadIdx.x; i < NBUCK; i += 256) cnt[i] = 0;
    __syncthreads();
    int base = blockIdx.x * 4096;
    int bp[16]; uint_t pl[16];
    #pragma unroll
    for (int it = 0; it < 16; ++it) {
        int e = base + it * 256 + threadIdx.x;
        if (e < nE) {
            int d = dst[e];
            int b = d >> 8;
            int p = atomicAdd(&cnt[b], 1);           // LDS atomic, block-local
            bp[it] = (b << 12) | p;                  // p < 4096
            pl[it] = ((uint_t)(d & 255) << 24) | (uint_t)src[e];
        } else bp[it] = -1;
    }
    __syncthreads();
    for (int i = threadIdx.x; i < NBUCK; i += 256)
        rbase[i] = atomicAdd(&pcur[i], cnt[i]);      // 391 global atomics/block
    __syncthreads();
    #pragma unroll
    for (int it = 0; it < 16; ++it) {
        if (bp[it] >= 0) {
            int b = bp[it] >> 12, p = bp[it] & 0xFFF;
            ebuf[rbase[b] + p] = pl[it];
        }
    }
}

// phase 2: block per bucket. LDS deg histogram + block scan -> rowptr (end offsets)
// + L2-local csr placement via LDS cursors. No global atomics at all.
__global__ __launch_bounds__(256) void k_build(
    const uint_t* __restrict__ ebuf, const int* __restrict__ bstart,
    const int* __restrict__ bsize, int* __restrict__ rowptr, int* __restrict__ csr)
{
    __shared__ int deg[256];
    __shared__ int cur[256];
    __shared__ int wsum[4];
    int b = blockIdx.x;
    int beg = bstart[b], n = bsize[b];
    int tid = threadIdx.x, lane = tid & 63, wv = tid >> 6;
    deg[tid] = 0;
    __syncthreads();
    for (int i = tid; i < n; i += 256) atomicAdd(&deg[ebuf[beg + i] >> 24], 1);
    __syncthreads();
    int v = deg[tid];
    int incl = v;
    #pragma unroll
    for (int o = 1; o < 64; o <<= 1) { int t = __shfl_up(incl, o); if (lane >= o) incl += t; }
    if (lane == 63) wsum[wv] = incl;
    __syncthreads();
    int wbase = 0;
    #pragma unroll
    for (int i = 0; i < 4; ++i) if (i < wv) wbase += wsum[i];
    incl += wbase;
    int idx = (b << 8) + tid;
    if (idx < N_NODES) rowptr[idx] = beg + incl;     // inclusive = end offset
    cur[tid] = beg + incl - v;                       // exclusive = start cursor
    __syncthreads();
    for (int i = tid; i < n; i += 256) {
        uint_t p = ebuf[beg + i];
        int j = (int)(p >> 24);
        int pos = atomicAdd(&cur[j], 1);             // LDS atomic
        csr[pos] = (int)(p & 0xFFFFFFu);
    }
}
// After k_build: node i's neighbors are csr[(i?rowptr[i-1]:0) .. rowptr[i])

// ================= weight prep: bf16 transpose W^T[F][K] =================

__global__ __launch_bounds__(256) void k_prep_w(
    const float* __restrict__ W2l, const float* __restrict__ W2r,
    const float* __restrict__ W3l, const float* __restrict__ W3r,
    ushort_t* __restrict__ wt2l, ushort_t* __restrict__ wt2r,
    ushort_t* __restrict__ wt3l, ushort_t* __restrict__ wt3r)
{
    int id = blockIdx.x * 256 + threadIdx.x;
    if (id < 16384)      { int j = id;         int f = j >> 7, k = j & 127; wt2l[j] = f2b(W2l[k*128 + f]); }
    else if (id < 32768) { int j = id - 16384; int f = j >> 7, k = j & 127; wt2r[j] = f2b(W2r[k*128 + f]); }
    else if (id < 40960) { int j = id - 32768; int f = j >> 7, k = j & 127; wt3l[j] = f2b(W3l[k*64 + f]); }
    else if (id < 49152) { int j = id - 40960; int f = j >> 7, k = j & 127; wt3r[j] = f2b(W3r[k*64 + f]); }
}

// ================= layer 1 (fused z-gather + MLP), wave per node, bf16 out =================

__global__ __launch_bounds__(256) void k_l1(
    const int* __restrict__ rowptr, const int* __restrict__ csr,
    const float* __restrict__ z,
    const float* __restrict__ W1l, const float* __restrict__ W1r,
    const float* __restrict__ b1, ushort_t* __restrict__ h1b, int n)
{
    int wid  = (blockIdx.x * 256 + threadIdx.x) >> 6;
    int lane = threadIdx.x & 63;
    if (wid >= n) return;
    int beg = wid ? rowptr[wid - 1] : 0;
    int end = rowptr[wid];
    float a0 = 0, a1 = 0, a2 = 0;
    for (int e = beg + lane; e < end; e += 64) {
        int s = csr[e];
        a0 += z[s * 3 + 0]; a1 += z[s * 3 + 1]; a2 += z[s * 3 + 2];
    }
    #pragma unroll
    for (int o = 32; o > 0; o >>= 1) {
        a0 += __shfl_xor(a0, o); a1 += __shfl_xor(a1, o); a2 += __shfl_xor(a2, o);
    }
    float iv = 1.0f / fmaxf((float)(end - beg), 1.0f);
    float m0 = a0 * iv, m1 = a1 * iv, m2 = a2 * iv;
    float z0 = z[wid * 3 + 0], z1 = z[wid * 3 + 1], z2 = z[wid * 3 + 2];
    int f0 = lane * 2;
    float2 bl  = *(const float2*)(b1 + f0);
    float2 l0 = *(const float2*)(W1l + 0*128 + f0);
    float2 l1 = *(const float2*)(W1l + 1*128 + f0);
    float2 l2 = *(const float2*)(W1l + 2*128 + f0);
    float2 r0 = *(const float2*)(W1r + 0*128 + f0);
    float2 r1 = *(const float2*)(W1r + 1*128 + f0);
    float2 r2 = *(const float2*)(W1r + 2*128 + f0);
    float v0 = bl.x + m0*l0.x + m1*l1.x + m2*l2.x + z0*r0.x + z1*r1.x + z2*r2.x;
    float v1 = bl.y + m0*l0.y + m1*l1.y + m2*l2.y + z0*r0.y + z1*r1.y + z2*r2.y;
    v0 = fmaxf(v0, 0.0f); v1 = fmaxf(v1, 0.0f);
    uint_t u = (uint_t)f2b(v0) | ((uint_t)f2b(v1) << 16);
    *(uint_t*)(h1b + (size_t)wid * 128 + f0) = u;
}

// ================= gathers (bf16 in), atomic-free =================

// F=128: wave per node, lane handles feats 2*lane, 2*lane+1; bf16 out
__global__ __launch_bounds__(256) void k_gather128(
    const int* __restrict__ rowptr, const int* __restrict__ csr,
    const ushort_t* __restrict__ x, ushort_t* __restrict__ out, int n)
{
    int wid  = (blockIdx.x * 256 + threadIdx.x) >> 6;
    int lane = threadIdx.x & 63;
    if (wid >= n) return;
    int beg = wid ? rowptr[wid - 1] : 0;
    int end = rowptr[wid];
    float a0 = 0.f, a1 = 0.f;
    for (int eb = beg; eb < end; eb += 64) {
        int cnt = min(64, end - eb);
        int my = (lane < cnt) ? csr[eb + lane] : 0;
        for (int j = 0; j < cnt; ++j) {
            int s = __shfl(my, j);
            uint_t v = *(const uint_t*)(x + (size_t)s * 128 + lane * 2);
            a0 += b2f((ushort_t)(v & 0xffffu));
            a1 += b2f((ushort_t)(v >> 16));
        }
    }
    float iv = 1.0f / fmaxf((float)(end - beg), 1.0f);
    uint_t u = (uint_t)f2b(a0 * iv) | ((uint_t)f2b(a1 * iv) << 16);
    *(uint_t*)(out + (size_t)wid * 128 + lane * 2) = u;
}

// F=64: half-wave per node, f32 out (consumed as post-GEMM addend)
__global__ __launch_bounds__(256) void k_gather64(
    const int* __restrict__ rowptr, const int* __restrict__ csr,
    const ushort_t* __restrict__ x, float* __restrict__ out, int n)
{
    int w    = (blockIdx.x * 256 + threadIdx.x) >> 6;
    int lane = threadIdx.x & 63;
    int sub  = lane >> 5, sl = lane & 31;
    int node = w * 2 + sub;
    if (node >= n) return;
    int beg = node ? rowptr[node - 1] : 0;
    int end = rowptr[node];
    float a0 = 0.f, a1 = 0.f;
    for (int eb = beg; eb < end; eb += 32) {
        int cnt = min(32, end - eb);
        int my = (sl < cnt) ? csr[eb + sl] : 0;
        for (int j = 0; j < cnt; ++j) {
            int s = __shfl(my, sub * 32 + j);
            uint_t v = *(const uint_t*)(x + (size_t)s * 64 + sl * 2);
            a0 += b2f((ushort_t)(v & 0xffffu));
            a1 += b2f((ushort_t)(v >> 16));
        }
    }
    float iv = 1.0f / fmaxf((float)(end - beg), 1.0f);
    float2 r; r.x = a0 * iv; r.y = a1 * iv;
    *(float2*)(out + (size_t)node * 64 + sl * 2) = r;
}

// ================= MFMA node GEMM =================
// out[i][f] = op( X1[i][:]@W1[:,f] (+ X2[i][:]@W2[:,f]) (+ pre[i][f]) (+ bias[f]) )
// X: [N_PAD][128] bf16 row-major. Wt: [F][128] bf16 (W transposed). 64 nodes/block, 4 waves.
template<int F, bool DUAL, bool ADDPRE, bool BIAS, bool RELU, bool OUTBF>
__global__ __launch_bounds__(256) void k_mfma(
    const ushort_t* __restrict__ X1, const ushort_t* __restrict__ Wt1,
    const ushort_t* __restrict__ X2, const ushort_t* __restrict__ Wt2,
    const float* __restrict__ pre, const float* __restrict__ bias,
    void* __restrict__ outv)
{
    constexpr int NB = F / 16;
    __shared__ short sX[(DUAL ? 2 : 1) * 64 * 128];
    const int tid  = threadIdx.x;
    const int wv   = tid >> 6, lane = tid & 63;
    const int hi   = lane >> 4, lo = lane & 15;
    const int base = blockIdx.x * 64;

    // stage X tiles: [64 rows][16 chunks of 16B], XOR-swizzled (c ^= row&7) -> 2-way-free ds_read
    #pragma unroll
    for (int m = 0; m < (DUAL ? 2 : 1); ++m) {
        const float4* gv = reinterpret_cast<const float4*>((m ? X2 : X1) + (size_t)base * 128);
        short* sb = &sX[m * 64 * 128];
        #pragma unroll
        for (int it = 0; it < 4; ++it) {
            int o = it * 256 + tid;
            int row = o >> 4, c = o & 15;
            float4 v = gv[row * 16 + c];
            *reinterpret_cast<float4*>(&sb[(row * 16 + (c ^ (row & 7))) * 8]) = v;
        }
    }
    __syncthreads();

    f32x4 acc[NB];
    #pragma unroll
    for (int b = 0; b < NB; ++b) acc[b] = (f32x4){0.f, 0.f, 0.f, 0.f};

    const int row = wv * 16 + lo;   // A-frag row within tile
    #pragma unroll
    for (int kk = 0; kk < 4; ++kk) {
        int sw = (kk * 4 + hi) ^ (row & 7);
        bf16x8 a1 = *reinterpret_cast<const bf16x8*>(&sX[(row * 16 + sw) * 8]);
        bf16x8 a2;
        if constexpr (DUAL)
            a2 = *reinterpret_cast<const bf16x8*>(&sX[64 * 128 + (row * 16 + sw) * 8]);
        #pragma unroll
        for (int b = 0; b < NB; ++b) {
            bf16x8 w1 = *reinterpret_cast<const bf16x8*>(Wt1 + (size_t)(b * 16 + lo) * 128 + kk * 32 + hi * 8);
            acc[b] = __builtin_amdgcn_mfma_f32_16x16x32_bf16(a1, w1, acc[b], 0, 0, 0);
            if constexpr (DUAL) {
                bf16x8 w2 = *reinterpret_cast<const bf16x8*>(Wt2 + (size_t)(b * 16 + lo) * 128 + kk * 32 + hi * 8);
                acc[b] = __builtin_amdgcn_mfma_f32_16x16x32_bf16(a2, w2, acc[b], 0, 0, 0);
            }
        }
    }

    // C/D layout: col = lane&15, row = (lane>>4)*4 + reg  [m89-verified]
    #pragma unroll
    for (int b = 0; b < NB; ++b) {
        #pragma unroll
        for (int r = 0; r < 4; ++r) {
            int node = base + wv * 16 + hi * 4 + r;
            int f    = b * 16 + lo;
            float v  = acc[b][r];
            if constexpr (ADDPRE) v += pre[(size_t)node * F + f];
            if constexpr (BIAS)   v += bias[f];
            if constexpr (RELU)   v = fmaxf(v, 0.0f);
            if constexpr (OUTBF)  ((ushort_t*)outv)[(size_t)node * F + f] = f2b(v);
            else                  ((float*)outv)[(size_t)node * F + f] = v;
        }
    }
}

// ================= output layer (f32 vector; K=64, F=40) =================

__global__ __launch_bounds__(256) void k_out(
    const float* __restrict__ h3, const float* __restrict__ W4,
    const float* __restrict__ b4, float* __restrict__ out, int n)
{
    int t = blockIdx.x * blockDim.x + threadIdx.x;
    int i = t / 40, f = t % 40;
    if (i >= n) return;
    float acc = b4[f];
    #pragma unroll
    for (int k = 0; k < 64; ++k) acc += h3[(size_t)i * 64 + k] * W4[k * 40 + f];
    out[t] = acc;
}

// ================= launch =================

extern "C" void kernel_launch(void* const* d_in, const int* in_sizes, int n_in,
                              void* d_out, int out_size, void* d_ws, size_t ws_size,
                              hipStream_t stream)
{
    const float* z   = (const float*)d_in[0];
    const int*   ei  = (const int*)d_in[1];
    const int*   src = ei;
    const int*   dst = ei + N_EDGES;
    const float* W1l = (const float*)d_in[2];
    const float* W1r = (const float*)d_in[3];
    const float* b1  = (const float*)d_in[4];
    const float* W2l = (const float*)d_in[5];
    const float* W2r = (const float*)d_in[6];
    const float* b2  = (const float*)d_in[7];
    const float* W3l = (const float*)d_in[8];
    const float* W3r = (const float*)d_in[9];
    const float* b3  = (const float*)d_in[10];
    const float* W4  = (const float*)d_in[11];
    const float* b4  = (const float*)d_in[12];
    float* out = (float*)d_out;

    // ---- workspace layout (all node arrays padded to N_PAD rows) ----
    ushort_t* h1b  = (ushort_t*)d_ws;                      // N_PAD*128 bf16
    ushort_t* aggb = h1b  + (size_t)N_PAD * 128;           // N_PAD*128 bf16
    ushort_t* h2b  = aggb + (size_t)N_PAD * 128;           // N_PAD*128 bf16
    ushort_t* t3b  = h2b  + (size_t)N_PAD * 128;           // N_PAD*64  bf16
    float* agg64   = (float*)(t3b + (size_t)N_PAD * 64);   // N_PAD*64  f32
    float* h3      = agg64 + (size_t)N_PAD * 64;           // N_PAD*64  f32
    int* rowptr    = (int*)(h3 + (size_t)N_PAD * 64);      // N ints
    int* csr       = rowptr + N_NODES;                     // E ints
    uint_t* ebuf   = (uint_t*)(csr + N_EDGES);             // E uints
    int* bsize     = (int*)(ebuf + N_EDGES);               // NBUCK ints
    int* bstart    = bsize + NBUCK;                        // NBUCK ints
    int* pcur      = bstart + NBUCK;                       // NBUCK ints
    ushort_t* wt2l = (ushort_t*)(pcur + NBUCK);            // 128*128
    ushort_t* wt2r = wt2l + 128 * 128;
    ushort_t* wt3l = wt2r + 128 * 128;                     // 64*128
    ushort_t* wt3r = wt3l + 64 * 128;

    // ---- CSR build (bucketed two-phase, LDS-histogram) ----
    hipMemsetAsync(bsize, 0, NBUCK * sizeof(int), stream);
    k_bcount<<<1563, 256, 0, stream>>>(dst, bsize, N_EDGES);
    k_bscan <<<1, 64, 0, stream>>>(bsize, bstart, pcur);
    k_bucket<<<391, 256, 0, stream>>>(src, dst, pcur, ebuf, N_EDGES);
    k_build <<<NBUCK, 256, 0, stream>>>(ebuf, bstart, bsize, rowptr, csr);

    // ---- weight prep (independent) ----
    k_prep_w<<<192, 256, 0, stream>>>(W2l, W2r, W3l, W3r, wt2l, wt2r, wt3l, wt3r);

    // ---- layer 1 ----
    k_l1<<<(N_NODES * 64 + 255) / 256, 256, 0, stream>>>(rowptr, csr, z, W1l, W1r, b1, h1b, N_NODES);

    // ---- layer 2 ----
    k_gather128<<<(N_NODES * 64 + 255) / 256, 256, 0, stream>>>(rowptr, csr, h1b, aggb, N_NODES);
    k_mfma<128, true,  false, true,  true,  true ><<<NBLK, 256, 0, stream>>>(
        aggb, wt2l, h1b, wt2r, nullptr, b2, h2b);

    // ---- layer 3 (pre-transform t3 = h2 @ W3l; mean is linear) ----
    k_mfma<64,  false, false, false, false, true ><<<NBLK, 256, 0, stream>>>(
        h2b, wt3l, nullptr, nullptr, nullptr, nullptr, t3b);
    k_gather64<<<((N_NODES + 1) / 2 * 64 + 255) / 256, 256, 0, stream>>>(rowptr, csr, t3b, agg64, N_NODES);
    k_mfma<64,  false, true,  true,  true,  false><<<NBLK, 256, 0, stream>>>(
        h2b, wt3r, nullptr, nullptr, agg64, b3, h3);

    // ---- output ----
    k_out<<<((size_t)N_NODES * 40 + 255) / 256, 256, 0, stream>>>(h3, W4, b4, out, N_NODES);
}

// Round 11
// 468.205 us; speedup vs baseline: 2.4086x; 1.1612x over previous
//
#include <hip/hip_runtime.h>

#define N_NODES 100000
#define N_EDGES 1600000
#define N_PAD   100032   // 1563 * 64
#define NBLK    1563
#define NBUCK   391      // ceil(N_NODES / 256), 256 nodes per bucket

typedef __attribute__((ext_vector_type(4))) float f32x4;
typedef __attribute__((ext_vector_type(8))) short bf16x8;
typedef unsigned short ushort_t;
typedef unsigned int uint_t;

__device__ __forceinline__ ushort_t f2b(float f) {
    uint_t u = __float_as_uint(f);
    uint_t r = (u + 0x7FFFu + ((u >> 16) & 1u)) >> 16;   // RNE
    return (ushort_t)r;
}
__device__ __forceinline__ float b2f(ushort_t h) {
    return __uint_as_float(((uint_t)h) << 16);
}
__device__ __forceinline__ void acc8(float* a, uint4 v) {
    a[0] += b2f((ushort_t)(v.x & 0xffffu)); a[1] += b2f((ushort_t)(v.x >> 16));
    a[2] += b2f((ushort_t)(v.y & 0xffffu)); a[3] += b2f((ushort_t)(v.y >> 16));
    a[4] += b2f((ushort_t)(v.z & 0xffffu)); a[5] += b2f((ushort_t)(v.z >> 16));
    a[6] += b2f((ushort_t)(v.w & 0xffffu)); a[7] += b2f((ushort_t)(v.w >> 16));
}

// ================= CSR build (bucketed, LDS-histogram) =================

// bucket sizes via per-block LDS histogram (391 global atomics/block, not 1/edge)
__global__ __launch_bounds__(256) void k_bcount(
    const int* __restrict__ dst, int* __restrict__ bsize, int nE)
{
    __shared__ int cnt[NBUCK];
    for (int i = threadIdx.x; i < NBUCK; i += 256) cnt[i] = 0;
    __syncthreads();
    int base = blockIdx.x * 1024;
    #pragma unroll
    for (int it = 0; it < 4; ++it) {
        int e = base + it * 256 + threadIdx.x;
        if (e < nE) atomicAdd(&cnt[dst[e] >> 8], 1);
    }
    __syncthreads();
    for (int i = threadIdx.x; i < NBUCK; i += 256)
        if (cnt[i]) atomicAdd(&bsize[i], cnt[i]);
}

// single wave: exclusive scan of bsize -> bstart, and init running cursors pcur
__global__ __launch_bounds__(64) void k_bscan(
    const int* __restrict__ bsize, int* __restrict__ bstart, int* __restrict__ pcur)
{
    int lane = threadIdx.x;
    int run = 0;
    for (int base = 0; base < NBUCK; base += 64) {
        int i = base + lane;
        int v = (i < NBUCK) ? bsize[i] : 0;
        int incl = v;
        #pragma unroll
        for (int o = 1; o < 64; o <<= 1) { int t = __shfl_up(incl, o); if (lane >= o) incl += t; }
        if (i < NBUCK) { int ex = run + incl - v; bstart[i] = ex; pcur[i] = ex; }
        run += __shfl(incl, 63);
    }
}

// phase 1: bin edges into ebuf (packed: local_dst<<24 | src), per-block LDS hist
// + one range-reservation atomic per bucket per block.
__global__ __launch_bounds__(256) void k_bucket(
    const int* __restrict__ src, const int* __restrict__ dst,
    int* __restrict__ pcur, uint_t* __restrict__ ebuf, int nE)
{
    __shared__ int cnt[NBUCK];
    __shared__ int rbase[NBUCK];
    for (int i = threadIdx.x; i < NBUCK; i += 256) cnt[i] = 0;
    __syncthreads();
    int base = blockIdx.x * 4096;
    int bp[16]; uint_t pl[16];
    #pragma unroll
    for (int it = 0; it < 16; ++it) {
        int e = base + it * 256 + threadIdx.x;
        if (e < nE) {
            int d = dst[e];
            int b = d >> 8;
            int p = atomicAdd(&cnt[b], 1);           // LDS atomic, block-local
            bp[it] = (b << 12) | p;                  // p < 4096
            pl[it] = ((uint_t)(d & 255) << 24) | (uint_t)src[e];
        } else bp[it] = -1;
    }
    __syncthreads();
    for (int i = threadIdx.x; i < NBUCK; i += 256)
        rbase[i] = atomicAdd(&pcur[i], cnt[i]);      // 391 global atomics/block
    __syncthreads();
    #pragma unroll
    for (int it = 0; it < 16; ++it) {
        if (bp[it] >= 0) {
            int b = bp[it] >> 12, p = bp[it] & 0xFFF;
            ebuf[rbase[b] + p] = pl[it];
        }
    }
}

// phase 2: block per bucket. LDS deg histogram + block scan -> rowptr (end offsets)
// + L2-local csr placement via LDS cursors. No global atomics at all.
__global__ __launch_bounds__(256) void k_build(
    const uint_t* __restrict__ ebuf, const int* __restrict__ bstart,
    const int* __restrict__ bsize, int* __restrict__ rowptr, int* __restrict__ csr)
{
    __shared__ int deg[256];
    __shared__ int cur[256];
    __shared__ int wsum[4];
    int b = blockIdx.x;
    int beg = bstart[b], n = bsize[b];
    int tid = threadIdx.x, lane = tid & 63, wv = tid >> 6;
    deg[tid] = 0;
    __syncthreads();
    for (int i = tid; i < n; i += 256) atomicAdd(&deg[ebuf[beg + i] >> 24], 1);
    __syncthreads();
    int v = deg[tid];
    int incl = v;
    #pragma unroll
    for (int o = 1; o < 64; o <<= 1) { int t = __shfl_up(incl, o); if (lane >= o) incl += t; }
    if (lane == 63) wsum[wv] = incl;
    __syncthreads();
    int wbase = 0;
    #pragma unroll
    for (int i = 0; i < 4; ++i) if (i < wv) wbase += wsum[i];
    incl += wbase;
    int idx = (b << 8) + tid;
    if (idx < N_NODES) rowptr[idx] = beg + incl;     // inclusive = end offset
    cur[tid] = beg + incl - v;                       // exclusive = start cursor
    __syncthreads();
    for (int i = tid; i < n; i += 256) {
        uint_t p = ebuf[beg + i];
        int j = (int)(p >> 24);
        int pos = atomicAdd(&cur[j], 1);             // LDS atomic
        csr[pos] = (int)(p & 0xFFFFFFu);
    }
}
// After k_build: node i's neighbors are csr[(i?rowptr[i-1]:0) .. rowptr[i])

// ================= weight prep: bf16 transpose W^T[F][K] =================

__global__ __launch_bounds__(256) void k_prep_w(
    const float* __restrict__ W2l, const float* __restrict__ W2r,
    const float* __restrict__ W3l, const float* __restrict__ W3r,
    ushort_t* __restrict__ wt2l, ushort_t* __restrict__ wt2r,
    ushort_t* __restrict__ wt3l, ushort_t* __restrict__ wt3r)
{
    int id = blockIdx.x * 256 + threadIdx.x;
    if (id < 16384)      { int j = id;         int f = j >> 7, k = j & 127; wt2l[j] = f2b(W2l[k*128 + f]); }
    else if (id < 32768) { int j = id - 16384; int f = j >> 7, k = j & 127; wt2r[j] = f2b(W2r[k*128 + f]); }
    else if (id < 40960) { int j = id - 32768; int f = j >> 7, k = j & 127; wt3l[j] = f2b(W3l[k*64 + f]); }
    else if (id < 49152) { int j = id - 40960; int f = j >> 7, k = j & 127; wt3r[j] = f2b(W3r[k*64 + f]); }
}

// ================= layer 1: 16-lane group per node (gather z + MLP), bf16 out =================

__global__ __launch_bounds__(256) void k_l1(
    const int* __restrict__ rowptr, const int* __restrict__ csr,
    const float* __restrict__ z,
    const float* __restrict__ W1l, const float* __restrict__ W1r,
    const float* __restrict__ b1, ushort_t* __restrict__ h1b, int n)
{
    int gid = (blockIdx.x * 256 + threadIdx.x) >> 4;
    int sl  = threadIdx.x & 15;
    if (gid >= n) return;
    int beg = gid ? rowptr[gid - 1] : 0;
    int end = rowptr[gid];
    float a0 = 0, a1 = 0, a2 = 0;
    for (int e = beg + sl; e < end; e += 16) {
        int s = csr[e];
        a0 += z[s * 3 + 0]; a1 += z[s * 3 + 1]; a2 += z[s * 3 + 2];
    }
    #pragma unroll
    for (int o = 8; o > 0; o >>= 1) {
        a0 += __shfl_xor(a0, o, 16); a1 += __shfl_xor(a1, o, 16); a2 += __shfl_xor(a2, o, 16);
    }
    float iv = 1.0f / fmaxf((float)(end - beg), 1.0f);
    float m0 = a0 * iv, m1 = a1 * iv, m2 = a2 * iv;
    float z0 = z[gid * 3 + 0], z1 = z[gid * 3 + 1], z2 = z[gid * 3 + 2];
    int f0 = sl * 8;
    uint_t pk[4];
    #pragma unroll
    for (int h = 0; h < 2; ++h) {
        float4 bl = *(const float4*)(b1 + f0 + h * 4);
        float4 l0 = *(const float4*)(W1l + 0*128 + f0 + h * 4);
        float4 l1 = *(const float4*)(W1l + 1*128 + f0 + h * 4);
        float4 l2 = *(const float4*)(W1l + 2*128 + f0 + h * 4);
        float4 r0 = *(const float4*)(W1r + 0*128 + f0 + h * 4);
        float4 r1 = *(const float4*)(W1r + 1*128 + f0 + h * 4);
        float4 r2 = *(const float4*)(W1r + 2*128 + f0 + h * 4);
        float v0 = fmaxf(bl.x + m0*l0.x + m1*l1.x + m2*l2.x + z0*r0.x + z1*r1.x + z2*r2.x, 0.0f);
        float v1 = fmaxf(bl.y + m0*l0.y + m1*l1.y + m2*l2.y + z0*r0.y + z1*r1.y + z2*r2.y, 0.0f);
        float v2 = fmaxf(bl.z + m0*l0.z + m1*l1.z + m2*l2.z + z0*r0.z + z1*r1.z + z2*r2.z, 0.0f);
        float v3 = fmaxf(bl.w + m0*l0.w + m1*l1.w + m2*l2.w + z0*r0.w + z1*r1.w + z2*r2.w, 0.0f);
        pk[h*2+0] = (uint_t)f2b(v0) | ((uint_t)f2b(v1) << 16);
        pk[h*2+1] = (uint_t)f2b(v2) | ((uint_t)f2b(v3) << 16);
    }
    uint4 u; u.x = pk[0]; u.y = pk[1]; u.z = pk[2]; u.w = pk[3];
    ((uint4*)(h1b + (size_t)gid * 128))[sl] = u;
}

// ================= gathers: 16-lane group per node, atomic-free =================

// F=128: lane sl covers feats 8*sl..8*sl+7 (uint4 = 16B per row); bf16 out
__global__ __launch_bounds__(256) void k_gather128(
    const int* __restrict__ rowptr, const int* __restrict__ csr,
    const ushort_t* __restrict__ x, ushort_t* __restrict__ out, int n)
{
    int gid = (blockIdx.x * 256 + threadIdx.x) >> 4;
    int sl  = threadIdx.x & 15;
    if (gid >= n) return;
    int beg = gid ? rowptr[gid - 1] : 0;
    int end = rowptr[gid];
    float a[8] = {0,0,0,0,0,0,0,0};
    int j = beg;
    for (; j + 2 <= end; j += 2) {
        int s0 = csr[j], s1 = csr[j + 1];
        uint4 v0 = ((const uint4*)(x + (size_t)s0 * 128))[sl];
        uint4 v1 = ((const uint4*)(x + (size_t)s1 * 128))[sl];
        acc8(a, v0); acc8(a, v1);
    }
    if (j < end) {
        uint4 v = ((const uint4*)(x + (size_t)csr[j] * 128))[sl];
        acc8(a, v);
    }
    float iv = 1.0f / fmaxf((float)(end - beg), 1.0f);
    uint4 u;
    u.x = (uint_t)f2b(a[0]*iv) | ((uint_t)f2b(a[1]*iv) << 16);
    u.y = (uint_t)f2b(a[2]*iv) | ((uint_t)f2b(a[3]*iv) << 16);
    u.z = (uint_t)f2b(a[4]*iv) | ((uint_t)f2b(a[5]*iv) << 16);
    u.w = (uint_t)f2b(a[6]*iv) | ((uint_t)f2b(a[7]*iv) << 16);
    ((uint4*)(out + (size_t)gid * 128))[sl] = u;
}

// F=64: lane sl covers feats 4*sl..4*sl+3 (uint2 = 8B per row); f32 out
__global__ __launch_bounds__(256) void k_gather64(
    const int* __restrict__ rowptr, const int* __restrict__ csr,
    const ushort_t* __restrict__ x, float* __restrict__ out, int n)
{
    int gid = (blockIdx.x * 256 + threadIdx.x) >> 4;
    int sl  = threadIdx.x & 15;
    if (gid >= n) return;
    int beg = gid ? rowptr[gid - 1] : 0;
    int end = rowptr[gid];
    float a0 = 0, a1 = 0, a2 = 0, a3 = 0;
    int j = beg;
    for (; j + 2 <= end; j += 2) {
        int s0 = csr[j], s1 = csr[j + 1];
        uint2 v0 = ((const uint2*)(x + (size_t)s0 * 64))[sl];
        uint2 v1 = ((const uint2*)(x + (size_t)s1 * 64))[sl];
        a0 += b2f((ushort_t)(v0.x & 0xffffu)); a1 += b2f((ushort_t)(v0.x >> 16));
        a2 += b2f((ushort_t)(v0.y & 0xffffu)); a3 += b2f((ushort_t)(v0.y >> 16));
        a0 += b2f((ushort_t)(v1.x & 0xffffu)); a1 += b2f((ushort_t)(v1.x >> 16));
        a2 += b2f((ushort_t)(v1.y & 0xffffu)); a3 += b2f((ushort_t)(v1.y >> 16));
    }
    if (j < end) {
        uint2 v = ((const uint2*)(x + (size_t)csr[j] * 64))[sl];
        a0 += b2f((ushort_t)(v.x & 0xffffu)); a1 += b2f((ushort_t)(v.x >> 16));
        a2 += b2f((ushort_t)(v.y & 0xffffu)); a3 += b2f((ushort_t)(v.y >> 16));
    }
    float iv = 1.0f / fmaxf((float)(end - beg), 1.0f);
    float4 r; r.x = a0 * iv; r.y = a1 * iv; r.z = a2 * iv; r.w = a3 * iv;
    ((float4*)(out + (size_t)gid * 64))[sl] = r;
}

// ================= MFMA node GEMM =================
// out[i][f] = op( X1[i][:]@W1[:,f] (+ X2[i][:]@W2[:,f]) (+ pre[i][f]) (+ bias[f]) )
// X: [N_PAD][128] bf16 row-major. Wt: [F][128] bf16 (W transposed). 64 nodes/block, 4 waves.
template<int F, bool DUAL, bool ADDPRE, bool BIAS, bool RELU, bool OUTBF>
__global__ __launch_bounds__(256) void k_mfma(
    const ushort_t* __restrict__ X1, const ushort_t* __restrict__ Wt1,
    const ushort_t* __restrict__ X2, const ushort_t* __restrict__ Wt2,
    const float* __restrict__ pre, const float* __restrict__ bias,
    void* __restrict__ outv)
{
    constexpr int NB = F / 16;
    __shared__ short sX[(DUAL ? 2 : 1) * 64 * 128];
    const int tid  = threadIdx.x;
    const int wv   = tid >> 6, lane = tid & 63;
    const int hi   = lane >> 4, lo = lane & 15;
    const int base = blockIdx.x * 64;

    // stage X tiles: [64 rows][16 chunks of 16B], XOR-swizzled (c ^= row&7) -> 2-way-free ds_read
    #pragma unroll
    for (int m = 0; m < (DUAL ? 2 : 1); ++m) {
        const float4* gv = reinterpret_cast<const float4*>((m ? X2 : X1) + (size_t)base * 128);
        short* sb = &sX[m * 64 * 128];
        #pragma unroll
        for (int it = 0; it < 4; ++it) {
            int o = it * 256 + tid;
            int row = o >> 4, c = o & 15;
            float4 v = gv[row * 16 + c];
            *reinterpret_cast<float4*>(&sb[(row * 16 + (c ^ (row & 7))) * 8]) = v;
        }
    }
    __syncthreads();

    f32x4 acc[NB];
    #pragma unroll
    for (int b = 0; b < NB; ++b) acc[b] = (f32x4){0.f, 0.f, 0.f, 0.f};

    const int row = wv * 16 + lo;   // A-frag row within tile
    #pragma unroll
    for (int kk = 0; kk < 4; ++kk) {
        int sw = (kk * 4 + hi) ^ (row & 7);
        bf16x8 a1 = *reinterpret_cast<const bf16x8*>(&sX[(row * 16 + sw) * 8]);
        bf16x8 a2;
        if constexpr (DUAL)
            a2 = *reinterpret_cast<const bf16x8*>(&sX[64 * 128 + (row * 16 + sw) * 8]);
        #pragma unroll
        for (int b = 0; b < NB; ++b) {
            bf16x8 w1 = *reinterpret_cast<const bf16x8*>(Wt1 + (size_t)(b * 16 + lo) * 128 + kk * 32 + hi * 8);
            acc[b] = __builtin_amdgcn_mfma_f32_16x16x32_bf16(a1, w1, acc[b], 0, 0, 0);
            if constexpr (DUAL) {
                bf16x8 w2 = *reinterpret_cast<const bf16x8*>(Wt2 + (size_t)(b * 16 + lo) * 128 + kk * 32 + hi * 8);
                acc[b] = __builtin_amdgcn_mfma_f32_16x16x32_bf16(a2, w2, acc[b], 0, 0, 0);
            }
        }
    }

    // C/D layout: col = lane&15, row = (lane>>4)*4 + reg  [m89-verified]
    #pragma unroll
    for (int b = 0; b < NB; ++b) {
        #pragma unroll
        for (int r = 0; r < 4; ++r) {
            int node = base + wv * 16 + hi * 4 + r;
            int f    = b * 16 + lo;
            float v  = acc[b][r];
            if constexpr (ADDPRE) v += pre[(size_t)node * F + f];
            if constexpr (BIAS)   v += bias[f];
            if constexpr (RELU)   v = fmaxf(v, 0.0f);
            if constexpr (OUTBF)  ((ushort_t*)outv)[(size_t)node * F + f] = f2b(v);
            else                  ((float*)outv)[(size_t)node * F + f] = v;
        }
    }
}

// ================= output layer (f32 vector; K=64, F=40) =================

__global__ __launch_bounds__(256) void k_out(
    const float* __restrict__ h3, const float* __restrict__ W4,
    const float* __restrict__ b4, float* __restrict__ out, int n)
{
    int t = blockIdx.x * blockDim.x + threadIdx.x;
    int i = t / 40, f = t % 40;
    if (i >= n) return;
    float acc = b4[f];
    #pragma unroll
    for (int k = 0; k < 64; ++k) acc += h3[(size_t)i * 64 + k] * W4[k * 40 + f];
    out[t] = acc;
}

// ================= launch =================

extern "C" void kernel_launch(void* const* d_in, const int* in_sizes, int n_in,
                              void* d_out, int out_size, void* d_ws, size_t ws_size,
                              hipStream_t stream)
{
    const float* z   = (const float*)d_in[0];
    const int*   ei  = (const int*)d_in[1];
    const int*   src = ei;
    const int*   dst = ei + N_EDGES;
    const float* W1l = (const float*)d_in[2];
    const float* W1r = (const float*)d_in[3];
    const float* b1  = (const float*)d_in[4];
    const float* W2l = (const float*)d_in[5];
    const float* W2r = (const float*)d_in[6];
    const float* b2  = (const float*)d_in[7];
    const float* W3l = (const float*)d_in[8];
    const float* W3r = (const float*)d_in[9];
    const float* b3  = (const float*)d_in[10];
    const float* W4  = (const float*)d_in[11];
    const float* b4  = (const float*)d_in[12];
    float* out = (float*)d_out;

    // ---- workspace layout (all node arrays padded to N_PAD rows) ----
    ushort_t* h1b  = (ushort_t*)d_ws;                      // N_PAD*128 bf16
    ushort_t* aggb = h1b  + (size_t)N_PAD * 128;           // N_PAD*128 bf16
    ushort_t* h2b  = aggb + (size_t)N_PAD * 128;           // N_PAD*128 bf16
    ushort_t* t3b  = h2b  + (size_t)N_PAD * 128;           // N_PAD*64  bf16
    float* agg64   = (float*)(t3b + (size_t)N_PAD * 64);   // N_PAD*64  f32
    float* h3      = agg64 + (size_t)N_PAD * 64;           // N_PAD*64  f32
    int* rowptr    = (int*)(h3 + (size_t)N_PAD * 64);      // N ints
    int* csr       = rowptr + N_NODES;                     // E ints
    uint_t* ebuf   = (uint_t*)(csr + N_EDGES);             // E uints
    int* bsize     = (int*)(ebuf + N_EDGES);               // NBUCK ints
    int* bstart    = bsize + NBUCK;                        // NBUCK ints
    int* pcur      = bstart + NBUCK;                       // NBUCK ints
    ushort_t* wt2l = (ushort_t*)(pcur + NBUCK);            // 128*128
    ushort_t* wt2r = wt2l + 128 * 128;
    ushort_t* wt3l = wt2r + 128 * 128;                     // 64*128
    ushort_t* wt3r = wt3l + 64 * 128;

    // ---- CSR build (bucketed two-phase, LDS-histogram) ----
    hipMemsetAsync(bsize, 0, NBUCK * sizeof(int), stream);
    k_bcount<<<1563, 256, 0, stream>>>(dst, bsize, N_EDGES);
    k_bscan <<<1, 64, 0, stream>>>(bsize, bstart, pcur);
    k_bucket<<<391, 256, 0, stream>>>(src, dst, pcur, ebuf, N_EDGES);
    k_build <<<NBUCK, 256, 0, stream>>>(ebuf, bstart, bsize, rowptr, csr);

    // ---- weight prep (independent) ----
    k_prep_w<<<192, 256, 0, stream>>>(W2l, W2r, W3l, W3r, wt2l, wt2r, wt3l, wt3r);

    // ---- layer 1 (16 nodes per block) ----
    k_l1<<<(N_NODES + 15) / 16, 256, 0, stream>>>(rowptr, csr, z, W1l, W1r, b1, h1b, N_NODES);

    // ---- layer 2 ----
    k_gather128<<<(N_NODES + 15) / 16, 256, 0, stream>>>(rowptr, csr, h1b, aggb, N_NODES);
    k_mfma<128, true,  false, true,  true,  true ><<<NBLK, 256, 0, stream>>>(
        aggb, wt2l, h1b, wt2r, nullptr, b2, h2b);

    // ---- layer 3 (pre-transform t3 = h2 @ W3l; mean is linear) ----
    k_mfma<64,  false, false, false, false, true ><<<NBLK, 256, 0, stream>>>(
        h2b, wt3l, nullptr, nullptr, nullptr, nullptr, t3b);
    k_gather64<<<(N_NODES + 15) / 16, 256, 0, stream>>>(rowptr, csr, t3b, agg64, N_NODES);
    k_mfma<64,  false, true,  true,  true,  false><<<NBLK, 256, 0, stream>>>(
        h2b, wt3r, nullptr, nullptr, agg64, b3, h3);

    // ---- output ----
    k_out<<<((size_t)N_NODES * 40 + 255) / 256, 256, 0, stream>>>(h3, W4, b4, out, N_NODES);
}

// Round 13
// 410.376 us; speedup vs baseline: 2.7481x; 1.1409x over previous
//
#include <hip/hip_runtime.h>

#define N_NODES 100000
#define N_EDGES 1600000
#define N_PAD   100032   // 1563 * 64
#define NBLK    1563
#define NBUCK   391      // ceil(N_NODES / 256), 256 nodes per bucket

typedef __attribute__((ext_vector_type(4))) float f32x4;
typedef __attribute__((ext_vector_type(8))) short bf16x8;
typedef unsigned short ushort_t;
typedef unsigned int uint_t;

__device__ __forceinline__ ushort_t f2b(float f) {
    uint_t u = __float_as_uint(f);
    uint_t r = (u + 0x7FFFu + ((u >> 16) & 1u)) >> 16;   // RNE
    return (ushort_t)r;
}
__device__ __forceinline__ float b2f(ushort_t h) {
    return __uint_as_float(((uint_t)h) << 16);
}
__device__ __forceinline__ void acc8(float* a, uint4 v) {
    a[0] += b2f((ushort_t)(v.x & 0xffffu)); a[1] += b2f((ushort_t)(v.x >> 16));
    a[2] += b2f((ushort_t)(v.y & 0xffffu)); a[3] += b2f((ushort_t)(v.y >> 16));
    a[4] += b2f((ushort_t)(v.z & 0xffffu)); a[5] += b2f((ushort_t)(v.z >> 16));
    a[6] += b2f((ushort_t)(v.w & 0xffffu)); a[7] += b2f((ushort_t)(v.w >> 16));
}

// ================= CSR build (bucketed, LDS-histogram) =================

__global__ __launch_bounds__(256) void k_bcount(
    const int* __restrict__ dst, int* __restrict__ bsize, int nE)
{
    __shared__ int cnt[NBUCK];
    for (int i = threadIdx.x; i < NBUCK; i += 256) cnt[i] = 0;
    __syncthreads();
    int base = blockIdx.x * 1024;
    #pragma unroll
    for (int it = 0; it < 4; ++it) {
        int e = base + it * 256 + threadIdx.x;
        if (e < nE) atomicAdd(&cnt[dst[e] >> 8], 1);
    }
    __syncthreads();
    for (int i = threadIdx.x; i < NBUCK; i += 256)
        if (cnt[i]) atomicAdd(&bsize[i], cnt[i]);
}

__global__ __launch_bounds__(64) void k_bscan(
    const int* __restrict__ bsize, int* __restrict__ bstart, int* __restrict__ pcur)
{
    int lane = threadIdx.x;
    int run = 0;
    for (int base = 0; base < NBUCK; base += 64) {
        int i = base + lane;
        int v = (i < NBUCK) ? bsize[i] : 0;
        int incl = v;
        #pragma unroll
        for (int o = 1; o < 64; o <<= 1) { int t = __shfl_up(incl, o); if (lane >= o) incl += t; }
        if (i < NBUCK) { int ex = run + incl - v; bstart[i] = ex; pcur[i] = ex; }
        run += __shfl(incl, 63);
    }
}

__global__ __launch_bounds__(256) void k_bucket(
    const int* __restrict__ src, const int* __restrict__ dst,
    int* __restrict__ pcur, uint_t* __restrict__ ebuf, int nE)
{
    __shared__ int cnt[NBUCK];
    __shared__ int rbase[NBUCK];
    for (int i = threadIdx.x; i < NBUCK; i += 256) cnt[i] = 0;
    __syncthreads();
    int base = blockIdx.x * 4096;
    int bp[16]; uint_t pl[16];
    #pragma unroll
    for (int it = 0; it < 16; ++it) {
        int e = base + it * 256 + threadIdx.x;
        if (e < nE) {
            int d = dst[e];
            int b = d >> 8;
            int p = atomicAdd(&cnt[b], 1);           // LDS atomic, block-local
            bp[it] = (b << 12) | p;                  // p < 4096
            pl[it] = ((uint_t)(d & 255) << 24) | (uint_t)src[e];
        } else bp[it] = -1;
    }
    __syncthreads();
    for (int i = threadIdx.x; i < NBUCK; i += 256)
        rbase[i] = atomicAdd(&pcur[i], cnt[i]);      // 391 global atomics/block
    __syncthreads();
    #pragma unroll
    for (int it = 0; it < 16; ++it) {
        if (bp[it] >= 0) {
            int b = bp[it] >> 12, p = bp[it] & 0xFFF;
            ebuf[rbase[b] + p] = pl[it];
        }
    }
}

__global__ __launch_bounds__(256) void k_build(
    const uint_t* __restrict__ ebuf, const int* __restrict__ bstart,
    const int* __restrict__ bsize, int* __restrict__ rowptr, int* __restrict__ csr)
{
    __shared__ int deg[256];
    __shared__ int cur[256];
    __shared__ int wsum[4];
    int b = blockIdx.x;
    int beg = bstart[b], n = bsize[b];
    int tid = threadIdx.x, lane = tid & 63, wv = tid >> 6;
    deg[tid] = 0;
    __syncthreads();
    for (int i = tid; i < n; i += 256) atomicAdd(&deg[ebuf[beg + i] >> 24], 1);
    __syncthreads();
    int v = deg[tid];
    int incl = v;
    #pragma unroll
    for (int o = 1; o < 64; o <<= 1) { int t = __shfl_up(incl, o); if (lane >= o) incl += t; }
    if (lane == 63) wsum[wv] = incl;
    __syncthreads();
    int wbase = 0;
    #pragma unroll
    for (int i = 0; i < 4; ++i) if (i < wv) wbase += wsum[i];
    incl += wbase;
    int idx = (b << 8) + tid;
    if (idx < N_NODES) rowptr[idx] = beg + incl;     // inclusive = end offset
    cur[tid] = beg + incl - v;                       // exclusive = start cursor
    __syncthreads();
    for (int i = tid; i < n; i += 256) {
        uint_t p = ebuf[beg + i];
        int j = (int)(p >> 24);
        int pos = atomicAdd(&cur[j], 1);             // LDS atomic
        csr[pos] = (int)(p & 0xFFFFFFu);
    }
}
// After k_build: node i's neighbors are csr[(i?rowptr[i-1]:0) .. rowptr[i])

// ================= weight prep: bf16 transpose W^T[F][K] =================

__global__ __launch_bounds__(256) void k_prep_w(
    const float* __restrict__ W2l, const float* __restrict__ W2r,
    const float* __restrict__ W3l, const float* __restrict__ W3r,
    ushort_t* __restrict__ wt2l, ushort_t* __restrict__ wt2r,
    ushort_t* __restrict__ wt3l, ushort_t* __restrict__ wt3r)
{
    int id = blockIdx.x * 256 + threadIdx.x;
    if (id < 16384)      { int j = id;         int f = j >> 7, k = j & 127; wt2l[j] = f2b(W2l[k*128 + f]); }
    else if (id < 32768) { int j = id - 16384; int f = j >> 7, k = j & 127; wt2r[j] = f2b(W2r[k*128 + f]); }
    else if (id < 40960) { int j = id - 32768; int f = j >> 7, k = j & 127; wt3l[j] = f2b(W3l[k*64 + f]); }
    else if (id < 49152) { int j = id - 40960; int f = j >> 7, k = j & 127; wt3r[j] = f2b(W3r[k*64 + f]); }
}

// ================= layer 1: 16-lane group per node (gather z + MLP), bf16 out =================

__global__ __launch_bounds__(256) void k_l1(
    const int* __restrict__ rowptr, const int* __restrict__ csr,
    const float* __restrict__ z,
    const float* __restrict__ W1l, const float* __restrict__ W1r,
    const float* __restrict__ b1, ushort_t* __restrict__ h1b, int n)
{
    int gid = (blockIdx.x * 256 + threadIdx.x) >> 4;
    int sl  = threadIdx.x & 15;
    if (gid >= n) return;
    int beg = gid ? rowptr[gid - 1] : 0;
    int end = rowptr[gid];
    float a0 = 0, a1 = 0, a2 = 0;
    for (int e = beg + sl; e < end; e += 16) {
        int s = csr[e];
        a0 += z[s * 3 + 0]; a1 += z[s * 3 + 1]; a2 += z[s * 3 + 2];
    }
    #pragma unroll
    for (int o = 8; o > 0; o >>= 1) {
        a0 += __shfl_xor(a0, o, 16); a1 += __shfl_xor(a1, o, 16); a2 += __shfl_xor(a2, o, 16);
    }
    float iv = 1.0f / fmaxf((float)(end - beg), 1.0f);
    float m0 = a0 * iv, m1 = a1 * iv, m2 = a2 * iv;
    float z0 = z[gid * 3 + 0], z1 = z[gid * 3 + 1], z2 = z[gid * 3 + 2];
    int f0 = sl * 8;
    uint_t pk[4];
    #pragma unroll
    for (int h = 0; h < 2; ++h) {
        float4 bl = *(const float4*)(b1 + f0 + h * 4);
        float4 l0 = *(const float4*)(W1l + 0*128 + f0 + h * 4);
        float4 l1 = *(const float4*)(W1l + 1*128 + f0 + h * 4);
        float4 l2 = *(const float4*)(W1l + 2*128 + f0 + h * 4);
        float4 r0 = *(const float4*)(W1r + 0*128 + f0 + h * 4);
        float4 r1 = *(const float4*)(W1r + 1*128 + f0 + h * 4);
        float4 r2 = *(const float4*)(W1r + 2*128 + f0 + h * 4);
        float v0 = fmaxf(bl.x + m0*l0.x + m1*l1.x + m2*l2.x + z0*r0.x + z1*r1.x + z2*r2.x, 0.0f);
        float v1 = fmaxf(bl.y + m0*l0.y + m1*l1.y + m2*l2.y + z0*r0.y + z1*r1.y + z2*r2.y, 0.0f);
        float v2 = fmaxf(bl.z + m0*l0.z + m1*l1.z + m2*l2.z + z0*r0.z + z1*r1.z + z2*r2.z, 0.0f);
        float v3 = fmaxf(bl.w + m0*l0.w + m1*l1.w + m2*l2.w + z0*r0.w + z1*r1.w + z2*r2.w, 0.0f);
        pk[h*2+0] = (uint_t)f2b(v0) | ((uint_t)f2b(v1) << 16);
        pk[h*2+1] = (uint_t)f2b(v2) | ((uint_t)f2b(v3) << 16);
    }
    uint4 u; u.x = pk[0]; u.y = pk[1]; u.z = pk[2]; u.w = pk[3];
    ((uint4*)(h1b + (size_t)gid * 128))[sl] = u;
}

// ================= gathers: 16-lane group per node, atomic-free =================

// F=128: lane sl covers feats 8*sl..8*sl+7 (uint4 = 16B per row); bf16 out
__global__ __launch_bounds__(256) void k_gather128(
    const int* __restrict__ rowptr, const int* __restrict__ csr,
    const ushort_t* __restrict__ x, ushort_t* __restrict__ out, int n)
{
    int gid = (blockIdx.x * 256 + threadIdx.x) >> 4;
    int sl  = threadIdx.x & 15;
    if (gid >= n) return;
    int beg = gid ? rowptr[gid - 1] : 0;
    int end = rowptr[gid];
    float a[8] = {0,0,0,0,0,0,0,0};
    int j = beg;
    for (; j + 2 <= end; j += 2) {
        int s0 = csr[j], s1 = csr[j + 1];
        uint4 v0 = ((const uint4*)(x + (size_t)s0 * 128))[sl];
        uint4 v1 = ((const uint4*)(x + (size_t)s1 * 128))[sl];
        acc8(a, v0); acc8(a, v1);
    }
    if (j < end) {
        uint4 v = ((const uint4*)(x + (size_t)csr[j] * 128))[sl];
        acc8(a, v);
    }
    float iv = 1.0f / fmaxf((float)(end - beg), 1.0f);
    uint4 u;
    u.x = (uint_t)f2b(a[0]*iv) | ((uint_t)f2b(a[1]*iv) << 16);
    u.y = (uint_t)f2b(a[2]*iv) | ((uint_t)f2b(a[3]*iv) << 16);
    u.z = (uint_t)f2b(a[4]*iv) | ((uint_t)f2b(a[5]*iv) << 16);
    u.w = (uint_t)f2b(a[6]*iv) | ((uint_t)f2b(a[7]*iv) << 16);
    ((uint4*)(out + (size_t)gid * 128))[sl] = u;
}

// F=64: lane sl covers feats 4*sl..4*sl+3 (uint2 = 8B per row); f32 out
__global__ __launch_bounds__(256) void k_gather64(
    const int* __restrict__ rowptr, const int* __restrict__ csr,
    const ushort_t* __restrict__ x, float* __restrict__ out, int n)
{
    int gid = (blockIdx.x * 256 + threadIdx.x) >> 4;
    int sl  = threadIdx.x & 15;
    if (gid >= n) return;
    int beg = gid ? rowptr[gid - 1] : 0;
    int end = rowptr[gid];
    float a0 = 0, a1 = 0, a2 = 0, a3 = 0;
    int j = beg;
    for (; j + 2 <= end; j += 2) {
        int s0 = csr[j], s1 = csr[j + 1];
        uint2 v0 = ((const uint2*)(x + (size_t)s0 * 64))[sl];
        uint2 v1 = ((const uint2*)(x + (size_t)s1 * 64))[sl];
        a0 += b2f((ushort_t)(v0.x & 0xffffu)); a1 += b2f((ushort_t)(v0.x >> 16));
        a2 += b2f((ushort_t)(v0.y & 0xffffu)); a3 += b2f((ushort_t)(v0.y >> 16));
        a0 += b2f((ushort_t)(v1.x & 0xffffu)); a1 += b2f((ushort_t)(v1.x >> 16));
        a2 += b2f((ushort_t)(v1.y & 0xffffu)); a3 += b2f((ushort_t)(v1.y >> 16));
    }
    if (j < end) {
        uint2 v = ((const uint2*)(x + (size_t)csr[j] * 64))[sl];
        a0 += b2f((ushort_t)(v.x & 0xffffu)); a1 += b2f((ushort_t)(v.x >> 16));
        a2 += b2f((ushort_t)(v.y & 0xffffu)); a3 += b2f((ushort_t)(v.y >> 16));
    }
    float iv = 1.0f / fmaxf((float)(end - beg), 1.0f);
    float4 r; r.x = a0 * iv; r.y = a1 * iv; r.z = a2 * iv; r.w = a3 * iv;
    ((float4*)(out + (size_t)gid * 64))[sl] = r;
}

// ================= MFMA node GEMM (wave owns F-slice; 4 A-strips per weight load) =================
// out[i][f] = op( X1[i][:]@W1[:,f] (+ X2[i][:]@W2[:,f]) (+ pre[i][f]) (+ bias[f]) )
// X: [N_PAD][128] bf16 row-major. Wt: [F][128] bf16 (W transposed). 64 nodes/block, 4 waves.
// Wave wv computes f-blocks [wv*BPW, (wv+1)*BPW) for ALL 64 nodes -> each weight
// fragment is loaded once and feeds 4 independent MFMAs (A-strips s=0..3).
template<int F, bool DUAL, bool ADDPRE, bool BIAS, bool RELU, bool OUTBF>
__global__ __launch_bounds__(256) void k_mfma(
    const ushort_t* __restrict__ X1, const ushort_t* __restrict__ Wt1,
    const ushort_t* __restrict__ X2, const ushort_t* __restrict__ Wt2,
    const float* __restrict__ pre, const float* __restrict__ bias,
    void* __restrict__ outv)
{
    constexpr int NB  = F / 16;
    constexpr int BPW = NB / 4;          // f-blocks per wave
    __shared__ short sX[(DUAL ? 2 : 1) * 64 * 128];
    const int tid  = threadIdx.x;
    const int wv   = tid >> 6, lane = tid & 63;
    const int hi   = lane >> 4, lo = lane & 15;
    const int base = blockIdx.x * 64;

    // stage X tiles: [64 rows][16 chunks of 16B], XOR-swizzled (c ^= row&7) -> 2-way-free ds_read
    #pragma unroll
    for (int m = 0; m < (DUAL ? 2 : 1); ++m) {
        const float4* gv = reinterpret_cast<const float4*>((m ? X2 : X1) + (size_t)base * 128);
        short* sb = &sX[m * 64 * 128];
        #pragma unroll
        for (int it = 0; it < 4; ++it) {
            int o = it * 256 + tid;
            int row = o >> 4, c = o & 15;
            float4 v = gv[row * 16 + c];
            *reinterpret_cast<float4*>(&sb[(row * 16 + (c ^ (row & 7))) * 8]) = v;
        }
    }
    __syncthreads();

    f32x4 acc[4][BPW];
    #pragma unroll
    for (int s = 0; s < 4; ++s)
        #pragma unroll
        for (int bb = 0; bb < BPW; ++bb) acc[s][bb] = (f32x4){0.f, 0.f, 0.f, 0.f};

    #pragma unroll
    for (int kk = 0; kk < 4; ++kk) {
        bf16x8 a1[4], a2[4];
        #pragma unroll
        for (int s = 0; s < 4; ++s) {
            int row = s * 16 + lo;
            int sw  = (kk * 4 + hi) ^ (row & 7);
            a1[s] = *reinterpret_cast<const bf16x8*>(&sX[(row * 16 + sw) * 8]);
            if constexpr (DUAL)
                a2[s] = *reinterpret_cast<const bf16x8*>(&sX[64 * 128 + (row * 16 + sw) * 8]);
        }
        #pragma unroll
        for (int bb = 0; bb < BPW; ++bb) {
            int fb = wv * BPW + bb;
            bf16x8 w1 = *reinterpret_cast<const bf16x8*>(Wt1 + (size_t)(fb * 16 + lo) * 128 + kk * 32 + hi * 8);
            #pragma unroll
            for (int s = 0; s < 4; ++s)
                acc[s][bb] = __builtin_amdgcn_mfma_f32_16x16x32_bf16(a1[s], w1, acc[s][bb], 0, 0, 0);
            if constexpr (DUAL) {
                bf16x8 w2 = *reinterpret_cast<const bf16x8*>(Wt2 + (size_t)(fb * 16 + lo) * 128 + kk * 32 + hi * 8);
                #pragma unroll
                for (int s = 0; s < 4; ++s)
                    acc[s][bb] = __builtin_amdgcn_mfma_f32_16x16x32_bf16(a2[s], w2, acc[s][bb], 0, 0, 0);
            }
        }
    }

    // C/D layout: col = lane&15, row = (lane>>4)*4 + reg  [m89-verified]
    #pragma unroll
    for (int s = 0; s < 4; ++s) {
        #pragma unroll
        for (int bb = 0; bb < BPW; ++bb) {
            int f = (wv * BPW + bb) * 16 + lo;
            #pragma unroll
            for (int r = 0; r < 4; ++r) {
                int node = base + s * 16 + hi * 4 + r;
                float v  = acc[s][bb][r];
                if constexpr (ADDPRE) v += pre[(size_t)node * F + f];
                if constexpr (BIAS)   v += bias[f];
                if constexpr (RELU)   v = fmaxf(v, 0.0f);
                if constexpr (OUTBF)  ((ushort_t*)outv)[(size_t)node * F + f] = f2b(v);
                else                  ((float*)outv)[(size_t)node * F + f] = v;
            }
        }
    }
}

// ================= output layer (f32 vector; K=64, F=40) =================

__global__ __launch_bounds__(256) void k_out(
    const float* __restrict__ h3, const float* __restrict__ W4,
    const float* __restrict__ b4, float* __restrict__ out, int n)
{
    int t = blockIdx.x * blockDim.x + threadIdx.x;
    int i = t / 40, f = t % 40;
    if (i >= n) return;
    float acc = b4[f];
    #pragma unroll
    for (int k = 0; k < 64; ++k) acc += h3[(size_t)i * 64 + k] * W4[k * 40 + f];
    out[t] = acc;
}

// ================= launch =================

extern "C" void kernel_launch(void* const* d_in, const int* in_sizes, int n_in,
                              void* d_out, int out_size, void* d_ws, size_t ws_size,
                              hipStream_t stream)
{
    const float* z   = (const float*)d_in[0];
    const int*   ei  = (const int*)d_in[1];
    const int*   src = ei;
    const int*   dst = ei + N_EDGES;
    const float* W1l = (const float*)d_in[2];
    const float* W1r = (const float*)d_in[3];
    const float* b1  = (const float*)d_in[4];
    const float* W2l = (const float*)d_in[5];
    const float* W2r = (const float*)d_in[6];
    const float* b2  = (const float*)d_in[7];
    const float* W3l = (const float*)d_in[8];
    const float* W3r = (const float*)d_in[9];
    const float* b3  = (const float*)d_in[10];
    const float* W4  = (const float*)d_in[11];
    const float* b4  = (const float*)d_in[12];
    float* out = (float*)d_out;

    // ---- workspace layout (all node arrays padded to N_PAD rows) ----
    ushort_t* h1b  = (ushort_t*)d_ws;                      // N_PAD*128 bf16
    ushort_t* aggb = h1b  + (size_t)N_PAD * 128;           // N_PAD*128 bf16
    ushort_t* h2b  = aggb + (size_t)N_PAD * 128;           // N_PAD*128 bf16
    ushort_t* t3b  = h2b  + (size_t)N_PAD * 128;           // N_PAD*64  bf16
    float* agg64   = (float*)(t3b + (size_t)N_PAD * 64);   // N_PAD*64  f32
    float* h3      = agg64 + (size_t)N_PAD * 64;           // N_PAD*64  f32
    int* rowptr    = (int*)(h3 + (size_t)N_PAD * 64);      // N ints
    int* csr       = rowptr + N_NODES;                     // E ints
    uint_t* ebuf   = (uint_t*)(csr + N_EDGES);             // E uints
    int* bsize     = (int*)(ebuf + N_EDGES);               // NBUCK ints
    int* bstart    = bsize + NBUCK;                        // NBUCK ints
    int* pcur      = bstart + NBUCK;                       // NBUCK ints
    ushort_t* wt2l = (ushort_t*)(pcur + NBUCK);            // 128*128
    ushort_t* wt2r = wt2l + 128 * 128;
    ushort_t* wt3l = wt2r + 128 * 128;                     // 64*128
    ushort_t* wt3r = wt3l + 64 * 128;

    // ---- CSR build (bucketed two-phase, LDS-histogram) ----
    hipMemsetAsync(bsize, 0, NBUCK * sizeof(int), stream);
    k_bcount<<<1563, 256, 0, stream>>>(dst, bsize, N_EDGES);
    k_bscan <<<1, 64, 0, stream>>>(bsize, bstart, pcur);
    k_bucket<<<391, 256, 0, stream>>>(src, dst, pcur, ebuf, N_EDGES);
    k_build <<<NBUCK, 256, 0, stream>>>(ebuf, bstart, bsize, rowptr, csr);

    // ---- weight prep (independent) ----
    k_prep_w<<<192, 256, 0, stream>>>(W2l, W2r, W3l, W3r, wt2l, wt2r, wt3l, wt3r);

    // ---- layer 1 (16 nodes per block) ----
    k_l1<<<(N_NODES + 15) / 16, 256, 0, stream>>>(rowptr, csr, z, W1l, W1r, b1, h1b, N_NODES);

    // ---- layer 2 ----
    k_gather128<<<(N_NODES + 15) / 16, 256, 0, stream>>>(rowptr, csr, h1b, aggb, N_NODES);
    k_mfma<128, true,  false, true,  true,  true ><<<NBLK, 256, 0, stream>>>(
        aggb, wt2l, h1b, wt2r, nullptr, b2, h2b);

    // ---- layer 3 (pre-transform t3 = h2 @ W3l; mean is linear) ----
    k_mfma<64,  false, false, false, false, true ><<<NBLK, 256, 0, stream>>>(
        h2b, wt3l, nullptr, nullptr, nullptr, nullptr, t3b);
    k_gather64<<<(N_NODES + 15) / 16, 256, 0, stream>>>(rowptr, csr, t3b, agg64, N_NODES);
    k_mfma<64,  false, true,  true,  true,  false><<<NBLK, 256, 0, stream>>>(
        h2b, wt3r, nullptr, nullptr, agg64, b3, h3);

    // ---- output ----
    k_out<<<((size_t)N_NODES * 40 + 255) / 256, 256, 0, stream>>>(h3, W4, b4, out, N_NODES);
}

// Round 14
// 349.163 us; speedup vs baseline: 3.2298x; 1.1753x over previous
//
#include <hip/hip_runtime.h>

#define N_NODES 100000
#define N_EDGES 1600000
#define N_PAD   100032   // 1563 * 64
#define NBLK    1563
#define NBUCK   391      // ceil(N_NODES / 256), 256 nodes per bucket

typedef __attribute__((ext_vector_type(4))) float f32x4;
typedef __attribute__((ext_vector_type(8))) short bf16x8;
typedef unsigned short ushort_t;
typedef unsigned int uint_t;

__device__ __forceinline__ ushort_t f2b(float f) {
    uint_t u = __float_as_uint(f);
    uint_t r = (u + 0x7FFFu + ((u >> 16) & 1u)) >> 16;   // RNE
    return (ushort_t)r;
}
__device__ __forceinline__ float b2f(ushort_t h) {
    return __uint_as_float(((uint_t)h) << 16);
}
__device__ __forceinline__ void acc8(float* a, uint4 v) {
    a[0] += b2f((ushort_t)(v.x & 0xffffu)); a[1] += b2f((ushort_t)(v.x >> 16));
    a[2] += b2f((ushort_t)(v.y & 0xffffu)); a[3] += b2f((ushort_t)(v.y >> 16));
    a[4] += b2f((ushort_t)(v.z & 0xffffu)); a[5] += b2f((ushort_t)(v.z >> 16));
    a[6] += b2f((ushort_t)(v.w & 0xffffu)); a[7] += b2f((ushort_t)(v.w >> 16));
}

// ================= CSR build (bucketed, LDS-histogram) =================

__global__ __launch_bounds__(256) void k_bcount(
    const int* __restrict__ dst, int* __restrict__ bsize, int nE)
{
    __shared__ int cnt[NBUCK];
    for (int i = threadIdx.x; i < NBUCK; i += 256) cnt[i] = 0;
    __syncthreads();
    int base = blockIdx.x * 1024;
    #pragma unroll
    for (int it = 0; it < 4; ++it) {
        int e = base + it * 256 + threadIdx.x;
        if (e < nE) atomicAdd(&cnt[dst[e] >> 8], 1);
    }
    __syncthreads();
    for (int i = threadIdx.x; i < NBUCK; i += 256)
        if (cnt[i]) atomicAdd(&bsize[i], cnt[i]);
}

__global__ __launch_bounds__(64) void k_bscan(
    const int* __restrict__ bsize, int* __restrict__ bstart, int* __restrict__ pcur)
{
    int lane = threadIdx.x;
    int run = 0;
    for (int base = 0; base < NBUCK; base += 64) {
        int i = base + lane;
        int v = (i < NBUCK) ? bsize[i] : 0;
        int incl = v;
        #pragma unroll
        for (int o = 1; o < 64; o <<= 1) { int t = __shfl_up(incl, o); if (lane >= o) incl += t; }
        if (i < NBUCK) { int ex = run + incl - v; bstart[i] = ex; pcur[i] = ex; }
        run += __shfl(incl, 63);
    }
}

__global__ __launch_bounds__(256) void k_bucket(
    const int* __restrict__ src, const int* __restrict__ dst,
    int* __restrict__ pcur, uint_t* __restrict__ ebuf, int nE)
{
    __shared__ int cnt[NBUCK];
    __shared__ int rbase[NBUCK];
    for (int i = threadIdx.x; i < NBUCK; i += 256) cnt[i] = 0;
    __syncthreads();
    int base = blockIdx.x * 4096;
    int bp[16]; uint_t pl[16];
    #pragma unroll
    for (int it = 0; it < 16; ++it) {
        int e = base + it * 256 + threadIdx.x;
        if (e < nE) {
            int d = dst[e];
            int b = d >> 8;
            int p = atomicAdd(&cnt[b], 1);           // LDS atomic, block-local
            bp[it] = (b << 12) | p;                  // p < 4096
            pl[it] = ((uint_t)(d & 255) << 24) | (uint_t)src[e];
        } else bp[it] = -1;
    }
    __syncthreads();
    for (int i = threadIdx.x; i < NBUCK; i += 256)
        rbase[i] = atomicAdd(&pcur[i], cnt[i]);      // 391 global atomics/block
    __syncthreads();
    #pragma unroll
    for (int it = 0; it < 16; ++it) {
        if (bp[it] >= 0) {
            int b = bp[it] >> 12, p = bp[it] & 0xFFF;
            ebuf[rbase[b] + p] = pl[it];
        }
    }
}

__global__ __launch_bounds__(256) void k_build(
    const uint_t* __restrict__ ebuf, const int* __restrict__ bstart,
    const int* __restrict__ bsize, int* __restrict__ rowptr, int* __restrict__ csr)
{
    __shared__ int deg[256];
    __shared__ int cur[256];
    __shared__ int wsum[4];
    int b = blockIdx.x;
    int beg = bstart[b], n = bsize[b];
    int tid = threadIdx.x, lane = tid & 63, wv = tid >> 6;
    deg[tid] = 0;
    __syncthreads();
    for (int i = tid; i < n; i += 256) atomicAdd(&deg[ebuf[beg + i] >> 24], 1);
    __syncthreads();
    int v = deg[tid];
    int incl = v;
    #pragma unroll
    for (int o = 1; o < 64; o <<= 1) { int t = __shfl_up(incl, o); if (lane >= o) incl += t; }
    if (lane == 63) wsum[wv] = incl;
    __syncthreads();
    int wbase = 0;
    #pragma unroll
    for (int i = 0; i < 4; ++i) if (i < wv) wbase += wsum[i];
    incl += wbase;
    int idx = (b << 8) + tid;
    if (idx < N_NODES) rowptr[idx] = beg + incl;     // inclusive = end offset
    cur[tid] = beg + incl - v;                       // exclusive = start cursor
    __syncthreads();
    for (int i = tid; i < n; i += 256) {
        uint_t p = ebuf[beg + i];
        int j = (int)(p >> 24);
        int pos = atomicAdd(&cur[j], 1);             // LDS atomic
        csr[pos] = (int)(p & 0xFFFFFFu);
    }
}
// After k_build: node i's neighbors are csr[(i?rowptr[i-1]:0) .. rowptr[i])

// ================= weight prep: bf16 transpose W^T[F][K] =================

__global__ __launch_bounds__(256) void k_prep_w(
    const float* __restrict__ W2l, const float* __restrict__ W2r,
    const float* __restrict__ W3l, const float* __restrict__ W3r,
    const float* __restrict__ W4,
    ushort_t* __restrict__ wt2l, ushort_t* __restrict__ wt2r,
    ushort_t* __restrict__ wt3l, ushort_t* __restrict__ wt3r,
    ushort_t* __restrict__ wt4)
{
    int id = blockIdx.x * 256 + threadIdx.x;
    if (id < 16384)      { int j = id;         int f = j >> 7, k = j & 127; wt2l[j] = f2b(W2l[k*128 + f]); }
    else if (id < 32768) { int j = id - 16384; int f = j >> 7, k = j & 127; wt2r[j] = f2b(W2r[k*128 + f]); }
    else if (id < 40960) { int j = id - 32768; int f = j >> 7, k = j & 127; wt3l[j] = f2b(W3l[k*64 + f]); }
    else if (id < 49152) { int j = id - 40960; int f = j >> 7, k = j & 127; wt3r[j] = f2b(W3r[k*64 + f]); }
    else if (id < 52224) { int j = id - 49152; int f = j >> 6, k = j & 63;  wt4[j]  = (f < 40) ? f2b(W4[k*40 + f]) : 0; }
}

// ================= layer 1: 16-lane group per node (gather z + MLP), bf16 out =================

__global__ __launch_bounds__(256) void k_l1(
    const int* __restrict__ rowptr, const int* __restrict__ csr,
    const float* __restrict__ z,
    const float* __restrict__ W1l, const float* __restrict__ W1r,
    const float* __restrict__ b1, ushort_t* __restrict__ h1b, int n)
{
    int gid = (blockIdx.x * 256 + threadIdx.x) >> 4;
    int sl  = threadIdx.x & 15;
    if (gid >= n) return;
    int beg = gid ? rowptr[gid - 1] : 0;
    int end = rowptr[gid];
    float a0 = 0, a1 = 0, a2 = 0;
    for (int e = beg + sl; e < end; e += 16) {
        int s = csr[e];
        a0 += z[s * 3 + 0]; a1 += z[s * 3 + 1]; a2 += z[s * 3 + 2];
    }
    #pragma unroll
    for (int o = 8; o > 0; o >>= 1) {
        a0 += __shfl_xor(a0, o, 16); a1 += __shfl_xor(a1, o, 16); a2 += __shfl_xor(a2, o, 16);
    }
    float iv = 1.0f / fmaxf((float)(end - beg), 1.0f);
    float m0 = a0 * iv, m1 = a1 * iv, m2 = a2 * iv;
    float z0 = z[gid * 3 + 0], z1 = z[gid * 3 + 1], z2 = z[gid * 3 + 2];
    int f0 = sl * 8;
    uint_t pk[4];
    #pragma unroll
    for (int h = 0; h < 2; ++h) {
        float4 bl = *(const float4*)(b1 + f0 + h * 4);
        float4 l0 = *(const float4*)(W1l + 0*128 + f0 + h * 4);
        float4 l1 = *(const float4*)(W1l + 1*128 + f0 + h * 4);
        float4 l2 = *(const float4*)(W1l + 2*128 + f0 + h * 4);
        float4 r0 = *(const float4*)(W1r + 0*128 + f0 + h * 4);
        float4 r1 = *(const float4*)(W1r + 1*128 + f0 + h * 4);
        float4 r2 = *(const float4*)(W1r + 2*128 + f0 + h * 4);
        float v0 = fmaxf(bl.x + m0*l0.x + m1*l1.x + m2*l2.x + z0*r0.x + z1*r1.x + z2*r2.x, 0.0f);
        float v1 = fmaxf(bl.y + m0*l0.y + m1*l1.y + m2*l2.y + z0*r0.y + z1*r1.y + z2*r2.y, 0.0f);
        float v2 = fmaxf(bl.z + m0*l0.z + m1*l1.z + m2*l2.z + z0*r0.z + z1*r1.z + z2*r2.z, 0.0f);
        float v3 = fmaxf(bl.w + m0*l0.w + m1*l1.w + m2*l2.w + z0*r0.w + z1*r1.w + z2*r2.w, 0.0f);
        pk[h*2+0] = (uint_t)f2b(v0) | ((uint_t)f2b(v1) << 16);
        pk[h*2+1] = (uint_t)f2b(v2) | ((uint_t)f2b(v3) << 16);
    }
    uint4 u; u.x = pk[0]; u.y = pk[1]; u.z = pk[2]; u.w = pk[3];
    ((uint4*)(h1b + (size_t)gid * 128))[sl] = u;
}

// ================= gathers: 16-lane group per node, atomic-free =================

// F=128: lane sl covers feats 8*sl..8*sl+7 (uint4 = 16B per row); bf16 out
__global__ __launch_bounds__(256) void k_gather128(
    const int* __restrict__ rowptr, const int* __restrict__ csr,
    const ushort_t* __restrict__ x, ushort_t* __restrict__ out, int n)
{
    int gid = (blockIdx.x * 256 + threadIdx.x) >> 4;
    int sl  = threadIdx.x & 15;
    if (gid >= n) return;
    int beg = gid ? rowptr[gid - 1] : 0;
    int end = rowptr[gid];
    float a[8] = {0,0,0,0,0,0,0,0};
    int j = beg;
    for (; j + 2 <= end; j += 2) {
        int s0 = csr[j], s1 = csr[j + 1];
        uint4 v0 = ((const uint4*)(x + (size_t)s0 * 128))[sl];
        uint4 v1 = ((const uint4*)(x + (size_t)s1 * 128))[sl];
        acc8(a, v0); acc8(a, v1);
    }
    if (j < end) {
        uint4 v = ((const uint4*)(x + (size_t)csr[j] * 128))[sl];
        acc8(a, v);
    }
    float iv = 1.0f / fmaxf((float)(end - beg), 1.0f);
    uint4 u;
    u.x = (uint_t)f2b(a[0]*iv) | ((uint_t)f2b(a[1]*iv) << 16);
    u.y = (uint_t)f2b(a[2]*iv) | ((uint_t)f2b(a[3]*iv) << 16);
    u.z = (uint_t)f2b(a[4]*iv) | ((uint_t)f2b(a[5]*iv) << 16);
    u.w = (uint_t)f2b(a[6]*iv) | ((uint_t)f2b(a[7]*iv) << 16);
    ((uint4*)(out + (size_t)gid * 128))[sl] = u;
}

// F=64: lane sl covers feats 4*sl..4*sl+3 (uint2 = 8B per row); f32 out
__global__ __launch_bounds__(256) void k_gather64(
    const int* __restrict__ rowptr, const int* __restrict__ csr,
    const ushort_t* __restrict__ x, float* __restrict__ out, int n)
{
    int gid = (blockIdx.x * 256 + threadIdx.x) >> 4;
    int sl  = threadIdx.x & 15;
    if (gid >= n) return;
    int beg = gid ? rowptr[gid - 1] : 0;
    int end = rowptr[gid];
    float a0 = 0, a1 = 0, a2 = 0, a3 = 0;
    int j = beg;
    for (; j + 2 <= end; j += 2) {
        int s0 = csr[j], s1 = csr[j + 1];
        uint2 v0 = ((const uint2*)(x + (size_t)s0 * 64))[sl];
        uint2 v1 = ((const uint2*)(x + (size_t)s1 * 64))[sl];
        a0 += b2f((ushort_t)(v0.x & 0xffffu)); a1 += b2f((ushort_t)(v0.x >> 16));
        a2 += b2f((ushort_t)(v0.y & 0xffffu)); a3 += b2f((ushort_t)(v0.y >> 16));
        a0 += b2f((ushort_t)(v1.x & 0xffffu)); a1 += b2f((ushort_t)(v1.x >> 16));
        a2 += b2f((ushort_t)(v1.y & 0xffffu)); a3 += b2f((ushort_t)(v1.y >> 16));
    }
    if (j < end) {
        uint2 v = ((const uint2*)(x + (size_t)csr[j] * 64))[sl];
        a0 += b2f((ushort_t)(v.x & 0xffffu)); a1 += b2f((ushort_t)(v.x >> 16));
        a2 += b2f((ushort_t)(v.y & 0xffffu)); a3 += b2f((ushort_t)(v.y >> 16));
    }
    float iv = 1.0f / fmaxf((float)(end - beg), 1.0f);
    float4 r; r.x = a0 * iv; r.y = a1 * iv; r.z = a2 * iv; r.w = a3 * iv;
    ((float4*)(out + (size_t)gid * 64))[sl] = r;
}

// ================= MFMA node GEMM (wave owns F-slice; 4 A-strips per weight load) =================
// out[i][f] = op( X1[i][:]@W1[:,f] (+ X2[i][:]@W2[:,f]) (+ bias[f]) )
template<int F, bool DUAL, bool BIAS, bool RELU, bool OUTBF>
__global__ __launch_bounds__(256) void k_mfma(
    const ushort_t* __restrict__ X1, const ushort_t* __restrict__ Wt1,
    const ushort_t* __restrict__ X2, const ushort_t* __restrict__ Wt2,
    const float* __restrict__ bias, void* __restrict__ outv)
{
    constexpr int NB  = F / 16;
    constexpr int BPW = NB / 4;          // f-blocks per wave
    __shared__ short sX[(DUAL ? 2 : 1) * 64 * 128];
    const int tid  = threadIdx.x;
    const int wv   = tid >> 6, lane = tid & 63;
    const int hi   = lane >> 4, lo = lane & 15;
    const int base = blockIdx.x * 64;

    // stage X tiles: [64 rows][16 chunks of 16B], XOR-swizzled (c ^= row&7)
    #pragma unroll
    for (int m = 0; m < (DUAL ? 2 : 1); ++m) {
        const float4* gv = reinterpret_cast<const float4*>((m ? X2 : X1) + (size_t)base * 128);
        short* sb = &sX[m * 64 * 128];
        #pragma unroll
        for (int it = 0; it < 4; ++it) {
            int o = it * 256 + tid;
            int row = o >> 4, c = o & 15;
            float4 v = gv[row * 16 + c];
            *reinterpret_cast<float4*>(&sb[(row * 16 + (c ^ (row & 7))) * 8]) = v;
        }
    }
    __syncthreads();

    f32x4 acc[4][BPW];
    #pragma unroll
    for (int s = 0; s < 4; ++s)
        #pragma unroll
        for (int bb = 0; bb < BPW; ++bb) acc[s][bb] = (f32x4){0.f, 0.f, 0.f, 0.f};

    #pragma unroll
    for (int kk = 0; kk < 4; ++kk) {
        bf16x8 a1[4], a2[4];
        #pragma unroll
        for (int s = 0; s < 4; ++s) {
            int row = s * 16 + lo;
            int sw  = (kk * 4 + hi) ^ (row & 7);
            a1[s] = *reinterpret_cast<const bf16x8*>(&sX[(row * 16 + sw) * 8]);
            if constexpr (DUAL)
                a2[s] = *reinterpret_cast<const bf16x8*>(&sX[64 * 128 + (row * 16 + sw) * 8]);
        }
        #pragma unroll
        for (int bb = 0; bb < BPW; ++bb) {
            int fb = wv * BPW + bb;
            bf16x8 w1 = *reinterpret_cast<const bf16x8*>(Wt1 + (size_t)(fb * 16 + lo) * 128 + kk * 32 + hi * 8);
            #pragma unroll
            for (int s = 0; s < 4; ++s)
                acc[s][bb] = __builtin_amdgcn_mfma_f32_16x16x32_bf16(a1[s], w1, acc[s][bb], 0, 0, 0);
            if constexpr (DUAL) {
                bf16x8 w2 = *reinterpret_cast<const bf16x8*>(Wt2 + (size_t)(fb * 16 + lo) * 128 + kk * 32 + hi * 8);
                #pragma unroll
                for (int s = 0; s < 4; ++s)
                    acc[s][bb] = __builtin_amdgcn_mfma_f32_16x16x32_bf16(a2[s], w2, acc[s][bb], 0, 0, 0);
            }
        }
    }

    // C/D layout: col = lane&15, row = (lane>>4)*4 + reg  [m89-verified]
    #pragma unroll
    for (int s = 0; s < 4; ++s) {
        #pragma unroll
        for (int bb = 0; bb < BPW; ++bb) {
            int f = (wv * BPW + bb) * 16 + lo;
            #pragma unroll
            for (int r = 0; r < 4; ++r) {
                int node = base + s * 16 + hi * 4 + r;
                float v  = acc[s][bb][r];
                if constexpr (BIAS)   v += bias[f];
                if constexpr (RELU)   v = fmaxf(v, 0.0f);
                if constexpr (OUTBF)  ((ushort_t*)outv)[(size_t)node * F + f] = f2b(v);
                else                  ((float*)outv)[(size_t)node * F + f] = v;
            }
        }
    }
}

// ================= fused layer-3-right + output GEMM =================
// h3 = relu(h2@W3r + agg64 + b3)  (to LDS bf16 tile)  ->  out = h3@W4 + b4
__global__ __launch_bounds__(256) void k_l3out(
    const ushort_t* __restrict__ X1, const ushort_t* __restrict__ Wt1,
    const float* __restrict__ pre, const float* __restrict__ bias,
    const ushort_t* __restrict__ Wt4, const float* __restrict__ b4,
    float* __restrict__ out)
{
    __shared__ short sX[64 * 128];    // h2 tile (swizzled, 16 chunks/row)
    __shared__ short sH[64 * 64];     // h3 tile (bf16, swizzled, 8 chunks/row)
    const int tid  = threadIdx.x;
    const int wv   = tid >> 6, lane = tid & 63;
    const int hi   = lane >> 4, lo = lane & 15;
    const int base = blockIdx.x * 64;

    {
        const float4* gv = reinterpret_cast<const float4*>(X1 + (size_t)base * 128);
        #pragma unroll
        for (int it = 0; it < 4; ++it) {
            int o = it * 256 + tid;
            int row = o >> 4, c = o & 15;
            float4 v = gv[row * 16 + c];
            *reinterpret_cast<float4*>(&sX[(row * 16 + (c ^ (row & 7))) * 8]) = v;
        }
    }
    __syncthreads();

    // stage 1: wave wv owns f-block wv (16 feats), all 64 nodes (4 A-strips)
    f32x4 acc[4];
    #pragma unroll
    for (int s = 0; s < 4; ++s) acc[s] = (f32x4){0.f, 0.f, 0.f, 0.f};
    #pragma unroll
    for (int kk = 0; kk < 4; ++kk) {
        bf16x8 w1 = *reinterpret_cast<const bf16x8*>(Wt1 + (size_t)(wv * 16 + lo) * 128 + kk * 32 + hi * 8);
        #pragma unroll
        for (int s = 0; s < 4; ++s) {
            int row = s * 16 + lo;
            int sw  = (kk * 4 + hi) ^ (row & 7);
            bf16x8 a = *reinterpret_cast<const bf16x8*>(&sX[(row * 16 + sw) * 8]);
            acc[s] = __builtin_amdgcn_mfma_f32_16x16x32_bf16(a, w1, acc[s], 0, 0, 0);
        }
    }

    // epilogue 1 -> sH (bf16, chunk-swizzled: c ^= row&7, 8 chunks/row)
    {
        int col = wv * 16 + lo;
        float bv = bias[col];
        #pragma unroll
        for (int s = 0; s < 4; ++s) {
            #pragma unroll
            for (int r = 0; r < 4; ++r) {
                int row  = s * 16 + hi * 4 + r;
                int node = base + row;
                float v = acc[s][r] + pre[(size_t)node * 64 + col] + bv;
                v = fmaxf(v, 0.0f);
                int c = (col >> 3) ^ (row & 7);
                sH[(row * 8 + c) * 8 + (col & 7)] = (short)f2b(v);
            }
        }
    }
    __syncthreads();

    // stage 2: out = h3 @ W4 + b4 ; wave wv owns A-strip wv (16 nodes), 3 f-blocks, K=64
    f32x4 acc2[3];
    #pragma unroll
    for (int fb = 0; fb < 3; ++fb) acc2[fb] = (f32x4){0.f, 0.f, 0.f, 0.f};
    #pragma unroll
    for (int kk = 0; kk < 2; ++kk) {
        int row = wv * 16 + lo;
        int sw  = (kk * 4 + hi) ^ (row & 7);
        bf16x8 a = *reinterpret_cast<const bf16x8*>(&sH[(row * 8 + sw) * 8]);
        #pragma unroll
        for (int fb = 0; fb < 3; ++fb) {
            bf16x8 w = *reinterpret_cast<const bf16x8*>(Wt4 + (size_t)(fb * 16 + lo) * 64 + kk * 32 + hi * 8);
            acc2[fb] = __builtin_amdgcn_mfma_f32_16x16x32_bf16(a, w, acc2[fb], 0, 0, 0);
        }
    }
    #pragma unroll
    for (int fb = 0; fb < 3; ++fb) {
        int f = fb * 16 + lo;
        if (f < 40) {
            float bv = b4[f];
            #pragma unroll
            for (int r = 0; r < 4; ++r) {
                int node = base + wv * 16 + hi * 4 + r;
                if (node < N_NODES)
                    out[(size_t)node * 40 + f] = acc2[fb][r] + bv;
            }
        }
    }
}

// ================= launch =================

extern "C" void kernel_launch(void* const* d_in, const int* in_sizes, int n_in,
                              void* d_out, int out_size, void* d_ws, size_t ws_size,
                              hipStream_t stream)
{
    const float* z   = (const float*)d_in[0];
    const int*   ei  = (const int*)d_in[1];
    const int*   src = ei;
    const int*   dst = ei + N_EDGES;
    const float* W1l = (const float*)d_in[2];
    const float* W1r = (const float*)d_in[3];
    const float* b1  = (const float*)d_in[4];
    const float* W2l = (const float*)d_in[5];
    const float* W2r = (const float*)d_in[6];
    const float* b2  = (const float*)d_in[7];
    const float* W3l = (const float*)d_in[8];
    const float* W3r = (const float*)d_in[9];
    const float* b3  = (const float*)d_in[10];
    const float* W4  = (const float*)d_in[11];
    const float* b4  = (const float*)d_in[12];
    float* out = (float*)d_out;

    // ---- workspace layout (all node arrays padded to N_PAD rows) ----
    ushort_t* h1b  = (ushort_t*)d_ws;                      // N_PAD*128 bf16
    ushort_t* aggb = h1b  + (size_t)N_PAD * 128;           // N_PAD*128 bf16
    ushort_t* h2b  = aggb + (size_t)N_PAD * 128;           // N_PAD*128 bf16
    ushort_t* t3b  = h2b  + (size_t)N_PAD * 128;           // N_PAD*64  bf16
    float* agg64   = (float*)(t3b + (size_t)N_PAD * 64);   // N_PAD*64  f32
    float* h3      = agg64 + (size_t)N_PAD * 64;           // N_PAD*64  f32 (unused now)
    int* rowptr    = (int*)(h3 + (size_t)N_PAD * 64);      // N ints
    int* csr       = rowptr + N_NODES;                     // E ints
    uint_t* ebuf   = (uint_t*)(csr + N_EDGES);             // E uints
    int* bsize     = (int*)(ebuf + N_EDGES);               // NBUCK ints
    int* bstart    = bsize + NBUCK;                        // NBUCK ints
    int* pcur      = bstart + NBUCK;                       // NBUCK ints
    ushort_t* wt2l = (ushort_t*)(pcur + NBUCK);            // 128*128
    ushort_t* wt2r = wt2l + 128 * 128;
    ushort_t* wt3l = wt2r + 128 * 128;                     // 64*128
    ushort_t* wt3r = wt3l + 64 * 128;
    ushort_t* wt4  = wt3r + 64 * 128;                      // 48*64

    // ---- CSR build (bucketed two-phase, LDS-histogram) ----
    hipMemsetAsync(bsize, 0, NBUCK * sizeof(int), stream);
    k_bcount<<<1563, 256, 0, stream>>>(dst, bsize, N_EDGES);
    k_bscan <<<1, 64, 0, stream>>>(bsize, bstart, pcur);
    k_bucket<<<391, 256, 0, stream>>>(src, dst, pcur, ebuf, N_EDGES);
    k_build <<<NBUCK, 256, 0, stream>>>(ebuf, bstart, bsize, rowptr, csr);

    // ---- weight prep (independent) ----
    k_prep_w<<<205, 256, 0, stream>>>(W2l, W2r, W3l, W3r, W4, wt2l, wt2r, wt3l, wt3r, wt4);

    // ---- layer 1 (16 nodes per block) ----
    k_l1<<<(N_NODES + 15) / 16, 256, 0, stream>>>(rowptr, csr, z, W1l, W1r, b1, h1b, N_NODES);

    // ---- layer 2 ----
    k_gather128<<<(N_NODES + 15) / 16, 256, 0, stream>>>(rowptr, csr, h1b, aggb, N_NODES);
    k_mfma<128, true,  true,  true,  true ><<<NBLK, 256, 0, stream>>>(
        aggb, wt2l, h1b, wt2r, b2, h2b);

    // ---- layer 3 (pre-transform t3 = h2 @ W3l; mean is linear) ----
    k_mfma<64,  false, false, false, true ><<<NBLK, 256, 0, stream>>>(
        h2b, wt3l, nullptr, nullptr, nullptr, t3b);
    k_gather64<<<(N_NODES + 15) / 16, 256, 0, stream>>>(rowptr, csr, t3b, agg64, N_NODES);
    k_l3out<<<NBLK, 256, 0, stream>>>(h2b, wt3r, agg64, b3, wt4, b4, out);
}

// Round 15
// 300.255 us; speedup vs baseline: 3.7559x; 1.1629x over previous
//
#include <hip/hip_runtime.h>

#define N_NODES 100000
#define N_EDGES 1600000
#define N_PAD   100032   // 1563 * 64
#define NBLK    1563
#define NBUCK   782      // ceil(N_NODES / 128), 128 nodes per bucket
#define BCAP    3072     // bucket capacity (mean 2046, sigma~45 -> >20 sigma headroom)

typedef __attribute__((ext_vector_type(4))) float f32x4;
typedef __attribute__((ext_vector_type(8))) short bf16x8;
typedef unsigned short ushort_t;
typedef unsigned int uint_t;

__device__ __forceinline__ ushort_t f2b(float f) {
    uint_t u = __float_as_uint(f);
    uint_t r = (u + 0x7FFFu + ((u >> 16) & 1u)) >> 16;   // RNE
    return (ushort_t)r;
}
__device__ __forceinline__ float b2f(ushort_t h) {
    return __uint_as_float(((uint_t)h) << 16);
}
__device__ __forceinline__ void acc8(float* a, uint4 v) {
    a[0] += b2f((ushort_t)(v.x & 0xffffu)); a[1] += b2f((ushort_t)(v.x >> 16));
    a[2] += b2f((ushort_t)(v.y & 0xffffu)); a[3] += b2f((ushort_t)(v.y >> 16));
    a[4] += b2f((ushort_t)(v.z & 0xffffu)); a[5] += b2f((ushort_t)(v.z >> 16));
    a[6] += b2f((ushort_t)(v.w & 0xffffu)); a[7] += b2f((ushort_t)(v.w >> 16));
}

// ================= weight prep (bf16 transpose W^T[F][K]) + pcur init =================

__global__ __launch_bounds__(256) void k_prep_w(
    const float* __restrict__ W2l, const float* __restrict__ W2r,
    const float* __restrict__ W3l, const float* __restrict__ W3r,
    const float* __restrict__ W4,
    ushort_t* __restrict__ wt2l, ushort_t* __restrict__ wt2r,
    ushort_t* __restrict__ wt3l, ushort_t* __restrict__ wt3r,
    ushort_t* __restrict__ wt4, int* __restrict__ pcur)
{
    int id = blockIdx.x * 256 + threadIdx.x;
    if (id < 16384)      { int j = id;         int f = j >> 7, k = j & 127; wt2l[j] = f2b(W2l[k*128 + f]); }
    else if (id < 32768) { int j = id - 16384; int f = j >> 7, k = j & 127; wt2r[j] = f2b(W2r[k*128 + f]); }
    else if (id < 40960) { int j = id - 32768; int f = j >> 7, k = j & 127; wt3l[j] = f2b(W3l[k*64 + f]); }
    else if (id < 49152) { int j = id - 40960; int f = j >> 7, k = j & 127; wt3r[j] = f2b(W3r[k*64 + f]); }
    else if (id < 52224) { int j = id - 49152; int f = j >> 6, k = j & 63;  wt4[j]  = (f < 40) ? f2b(W4[k*40 + f]) : 0; }
    else if (id < 52224 + NBUCK) { int j = id - 52224; pcur[j] = j * BCAP; }
}

// ================= CSR build (fixed-capacity buckets) =================

// phase 1: bin edges into fixed-stride ebuf (packed: local_dst<<24 | src),
// per-block LDS hist + one range-reservation atomic per bucket per block.
__global__ __launch_bounds__(256) void k_bucket(
    const int* __restrict__ src, const int* __restrict__ dst,
    int* __restrict__ pcur, uint_t* __restrict__ ebuf, int nE)
{
    __shared__ int cnt[NBUCK];
    __shared__ int rbase[NBUCK];
    for (int i = threadIdx.x; i < NBUCK; i += 256) cnt[i] = 0;
    __syncthreads();
    int base = blockIdx.x * 4096;
    int bp[16]; uint_t pl[16];
    #pragma unroll
    for (int it = 0; it < 16; ++it) {
        int e = base + it * 256 + threadIdx.x;
        if (e < nE) {
            int d = dst[e];
            int b = d >> 7;
            int p = atomicAdd(&cnt[b], 1);           // LDS atomic, block-local
            bp[it] = (b << 12) | p;                  // p < 4096
            pl[it] = ((uint_t)(d & 127) << 24) | (uint_t)src[e];
        } else bp[it] = -1;
    }
    __syncthreads();
    for (int i = threadIdx.x; i < NBUCK; i += 256)
        rbase[i] = atomicAdd(&pcur[i], cnt[i]);      // NBUCK global atomics/block
    __syncthreads();
    #pragma unroll
    for (int it = 0; it < 16; ++it) {
        if (bp[it] >= 0) {
            int b = bp[it] >> 12, p = bp[it] & 0xFFF;
            ebuf[rbase[b] + p] = pl[it];
        }
    }
}

// phase 2: block per bucket (128 nodes). LDS deg histogram + scan -> rowbe {beg,end}
// + L2-local csr placement via LDS cursors. No global atomics.
__global__ __launch_bounds__(256) void k_build(
    const uint_t* __restrict__ ebuf, const int* __restrict__ pcur,
    int2* __restrict__ rowbe, int* __restrict__ csr)
{
    __shared__ int deg[128];
    __shared__ int cur[128];
    __shared__ int wsum[2];
    int b = blockIdx.x;
    int beg = b * BCAP, n = pcur[b] - beg;
    int tid = threadIdx.x, lane = tid & 63, wv = tid >> 6;
    if (tid < 128) deg[tid] = 0;
    __syncthreads();
    for (int i = tid; i < n; i += 256) atomicAdd(&deg[ebuf[beg + i] >> 24], 1);
    __syncthreads();
    int v = 0, incl = 0;
    if (tid < 128) {
        v = deg[tid];
        incl = v;
        #pragma unroll
        for (int o = 1; o < 64; o <<= 1) { int t = __shfl_up(incl, o); if (lane >= o) incl += t; }
        if (lane == 63) wsum[wv] = incl;
    }
    __syncthreads();
    if (tid < 128) {
        if (wv == 1) incl += wsum[0];
        int idx = (b << 7) + tid;
        if (idx < N_NODES) rowbe[idx] = make_int2(beg + incl - v, beg + incl);
        cur[tid] = beg + incl - v;
    }
    __syncthreads();
    for (int i = tid; i < n; i += 256) {
        uint_t p = ebuf[beg + i];
        int pos = atomicAdd(&cur[p >> 24], 1);       // LDS atomic
        csr[pos] = (int)(p & 0xFFFFFFu);
    }
}
// After k_build: node i's neighbors are csr[rowbe[i].x .. rowbe[i].y)

// ================= layer 1: 16-lane group per node (gather z + MLP), bf16 out =================

__global__ __launch_bounds__(256) void k_l1(
    const int2* __restrict__ rowbe, const int* __restrict__ csr,
    const float* __restrict__ z,
    const float* __restrict__ W1l, const float* __restrict__ W1r,
    const float* __restrict__ b1, ushort_t* __restrict__ h1b, int n)
{
    int gid = (blockIdx.x * 256 + threadIdx.x) >> 4;
    int sl  = threadIdx.x & 15;
    if (gid >= n) return;
    int2 be = rowbe[gid];
    int beg = be.x, end = be.y;
    float a0 = 0, a1 = 0, a2 = 0;
    for (int e = beg + sl; e < end; e += 16) {
        int s = csr[e];
        a0 += z[s * 3 + 0]; a1 += z[s * 3 + 1]; a2 += z[s * 3 + 2];
    }
    #pragma unroll
    for (int o = 8; o > 0; o >>= 1) {
        a0 += __shfl_xor(a0, o, 16); a1 += __shfl_xor(a1, o, 16); a2 += __shfl_xor(a2, o, 16);
    }
    float iv = 1.0f / fmaxf((float)(end - beg), 1.0f);
    float m0 = a0 * iv, m1 = a1 * iv, m2 = a2 * iv;
    float z0 = z[gid * 3 + 0], z1 = z[gid * 3 + 1], z2 = z[gid * 3 + 2];
    int f0 = sl * 8;
    uint_t pk[4];
    #pragma unroll
    for (int h = 0; h < 2; ++h) {
        float4 bl = *(const float4*)(b1 + f0 + h * 4);
        float4 l0 = *(const float4*)(W1l + 0*128 + f0 + h * 4);
        float4 l1 = *(const float4*)(W1l + 1*128 + f0 + h * 4);
        float4 l2 = *(const float4*)(W1l + 2*128 + f0 + h * 4);
        float4 r0 = *(const float4*)(W1r + 0*128 + f0 + h * 4);
        float4 r1 = *(const float4*)(W1r + 1*128 + f0 + h * 4);
        float4 r2 = *(const float4*)(W1r + 2*128 + f0 + h * 4);
        float v0 = fmaxf(bl.x + m0*l0.x + m1*l1.x + m2*l2.x + z0*r0.x + z1*r1.x + z2*r2.x, 0.0f);
        float v1 = fmaxf(bl.y + m0*l0.y + m1*l1.y + m2*l2.y + z0*r0.y + z1*r1.y + z2*r2.y, 0.0f);
        float v2 = fmaxf(bl.z + m0*l0.z + m1*l1.z + m2*l2.z + z0*r0.z + z1*r1.z + z2*r2.z, 0.0f);
        float v3 = fmaxf(bl.w + m0*l0.w + m1*l1.w + m2*l2.w + z0*r0.w + z1*r1.w + z2*r2.w, 0.0f);
        pk[h*2+0] = (uint_t)f2b(v0) | ((uint_t)f2b(v1) << 16);
        pk[h*2+1] = (uint_t)f2b(v2) | ((uint_t)f2b(v3) << 16);
    }
    uint4 u; u.x = pk[0]; u.y = pk[1]; u.z = pk[2]; u.w = pk[3];
    ((uint4*)(h1b + (size_t)gid * 128))[sl] = u;
}

// ================= gathers: 16-lane group per node, atomic-free =================

// F=128: lane sl covers feats 8*sl..8*sl+7 (uint4 = 16B per row); bf16 out
__global__ __launch_bounds__(256) void k_gather128(
    const int2* __restrict__ rowbe, const int* __restrict__ csr,
    const ushort_t* __restrict__ x, ushort_t* __restrict__ out, int n)
{
    int gid = (blockIdx.x * 256 + threadIdx.x) >> 4;
    int sl  = threadIdx.x & 15;
    if (gid >= n) return;
    int2 be = rowbe[gid];
    int beg = be.x, end = be.y;
    float a[8] = {0,0,0,0,0,0,0,0};
    int j = beg;
    for (; j + 2 <= end; j += 2) {
        int s0 = csr[j], s1 = csr[j + 1];
        uint4 v0 = ((const uint4*)(x + (size_t)s0 * 128))[sl];
        uint4 v1 = ((const uint4*)(x + (size_t)s1 * 128))[sl];
        acc8(a, v0); acc8(a, v1);
    }
    if (j < end) {
        uint4 v = ((const uint4*)(x + (size_t)csr[j] * 128))[sl];
        acc8(a, v);
    }
    float iv = 1.0f / fmaxf((float)(end - beg), 1.0f);
    uint4 u;
    u.x = (uint_t)f2b(a[0]*iv) | ((uint_t)f2b(a[1]*iv) << 16);
    u.y = (uint_t)f2b(a[2]*iv) | ((uint_t)f2b(a[3]*iv) << 16);
    u.z = (uint_t)f2b(a[4]*iv) | ((uint_t)f2b(a[5]*iv) << 16);
    u.w = (uint_t)f2b(a[6]*iv) | ((uint_t)f2b(a[7]*iv) << 16);
    ((uint4*)(out + (size_t)gid * 128))[sl] = u;
}

// F=64: lane sl covers feats 4*sl..4*sl+3 (uint2 = 8B per row); f32 out
__global__ __launch_bounds__(256) void k_gather64(
    const int2* __restrict__ rowbe, const int* __restrict__ csr,
    const ushort_t* __restrict__ x, float* __restrict__ out, int n)
{
    int gid = (blockIdx.x * 256 + threadIdx.x) >> 4;
    int sl  = threadIdx.x & 15;
    if (gid >= n) return;
    int2 be = rowbe[gid];
    int beg = be.x, end = be.y;
    float a0 = 0, a1 = 0, a2 = 0, a3 = 0;
    int j = beg;
    for (; j + 2 <= end; j += 2) {
        int s0 = csr[j], s1 = csr[j + 1];
        uint2 v0 = ((const uint2*)(x + (size_t)s0 * 64))[sl];
        uint2 v1 = ((const uint2*)(x + (size_t)s1 * 64))[sl];
        a0 += b2f((ushort_t)(v0.x & 0xffffu)); a1 += b2f((ushort_t)(v0.x >> 16));
        a2 += b2f((ushort_t)(v0.y & 0xffffu)); a3 += b2f((ushort_t)(v0.y >> 16));
        a0 += b2f((ushort_t)(v1.x & 0xffffu)); a1 += b2f((ushort_t)(v1.x >> 16));
        a2 += b2f((ushort_t)(v1.y & 0xffffu)); a3 += b2f((ushort_t)(v1.y >> 16));
    }
    if (j < end) {
        uint2 v = ((const uint2*)(x + (size_t)csr[j] * 64))[sl];
        a0 += b2f((ushort_t)(v.x & 0xffffu)); a1 += b2f((ushort_t)(v.x >> 16));
        a2 += b2f((ushort_t)(v.y & 0xffffu)); a3 += b2f((ushort_t)(v.y >> 16));
    }
    float iv = 1.0f / fmaxf((float)(end - beg), 1.0f);
    float4 r; r.x = a0 * iv; r.y = a1 * iv; r.z = a2 * iv; r.w = a3 * iv;
    ((float4*)(out + (size_t)gid * 64))[sl] = r;
}

// ================= MFMA node GEMM (wave owns F-slice; 4 A-strips per weight load) =================
// out[i][f] = op( X1[i][:]@W1[:,f] (+ X2[i][:]@W2[:,f]) (+ bias[f]) )
template<int F, bool DUAL, bool BIAS, bool RELU, bool OUTBF>
__global__ __launch_bounds__(256) void k_mfma(
    const ushort_t* __restrict__ X1, const ushort_t* __restrict__ Wt1,
    const ushort_t* __restrict__ X2, const ushort_t* __restrict__ Wt2,
    const float* __restrict__ bias, void* __restrict__ outv)
{
    constexpr int NB  = F / 16;
    constexpr int BPW = NB / 4;          // f-blocks per wave
    __shared__ short sX[(DUAL ? 2 : 1) * 64 * 128];
    const int tid  = threadIdx.x;
    const int wv   = tid >> 6, lane = tid & 63;
    const int hi   = lane >> 4, lo = lane & 15;
    const int base = blockIdx.x * 64;

    #pragma unroll
    for (int m = 0; m < (DUAL ? 2 : 1); ++m) {
        const float4* gv = reinterpret_cast<const float4*>((m ? X2 : X1) + (size_t)base * 128);
        short* sb = &sX[m * 64 * 128];
        #pragma unroll
        for (int it = 0; it < 4; ++it) {
            int o = it * 256 + tid;
            int row = o >> 4, c = o & 15;
            float4 v = gv[row * 16 + c];
            *reinterpret_cast<float4*>(&sb[(row * 16 + (c ^ (row & 7))) * 8]) = v;
        }
    }
    __syncthreads();

    f32x4 acc[4][BPW];
    #pragma unroll
    for (int s = 0; s < 4; ++s)
        #pragma unroll
        for (int bb = 0; bb < BPW; ++bb) acc[s][bb] = (f32x4){0.f, 0.f, 0.f, 0.f};

    #pragma unroll
    for (int kk = 0; kk < 4; ++kk) {
        bf16x8 a1[4], a2[4];
        #pragma unroll
        for (int s = 0; s < 4; ++s) {
            int row = s * 16 + lo;
            int sw  = (kk * 4 + hi) ^ (row & 7);
            a1[s] = *reinterpret_cast<const bf16x8*>(&sX[(row * 16 + sw) * 8]);
            if constexpr (DUAL)
                a2[s] = *reinterpret_cast<const bf16x8*>(&sX[64 * 128 + (row * 16 + sw) * 8]);
        }
        #pragma unroll
        for (int bb = 0; bb < BPW; ++bb) {
            int fb = wv * BPW + bb;
            bf16x8 w1 = *reinterpret_cast<const bf16x8*>(Wt1 + (size_t)(fb * 16 + lo) * 128 + kk * 32 + hi * 8);
            #pragma unroll
            for (int s = 0; s < 4; ++s)
                acc[s][bb] = __builtin_amdgcn_mfma_f32_16x16x32_bf16(a1[s], w1, acc[s][bb], 0, 0, 0);
            if constexpr (DUAL) {
                bf16x8 w2 = *reinterpret_cast<const bf16x8*>(Wt2 + (size_t)(fb * 16 + lo) * 128 + kk * 32 + hi * 8);
                #pragma unroll
                for (int s = 0; s < 4; ++s)
                    acc[s][bb] = __builtin_amdgcn_mfma_f32_16x16x32_bf16(a2[s], w2, acc[s][bb], 0, 0, 0);
            }
        }
    }

    // C/D layout: col = lane&15, row = (lane>>4)*4 + reg  [m89-verified]
    #pragma unroll
    for (int s = 0; s < 4; ++s) {
        #pragma unroll
        for (int bb = 0; bb < BPW; ++bb) {
            int f = (wv * BPW + bb) * 16 + lo;
            #pragma unroll
            for (int r = 0; r < 4; ++r) {
                int node = base + s * 16 + hi * 4 + r;
                float v  = acc[s][bb][r];
                if constexpr (BIAS)   v += bias[f];
                if constexpr (RELU)   v = fmaxf(v, 0.0f);
                if constexpr (OUTBF)  ((ushort_t*)outv)[(size_t)node * F + f] = f2b(v);
                else                  ((float*)outv)[(size_t)node * F + f] = v;
            }
        }
    }
}

// ================= fused layer-3-right + output GEMM =================
// h3 = relu(h2@W3r + agg64 + b3)  (to LDS bf16 tile)  ->  out = h3@W4 + b4
__global__ __launch_bounds__(256) void k_l3out(
    const ushort_t* __restrict__ X1, const ushort_t* __restrict__ Wt1,
    const float* __restrict__ pre, const float* __restrict__ bias,
    const ushort_t* __restrict__ Wt4, const float* __restrict__ b4,
    float* __restrict__ out)
{
    __shared__ short sX[64 * 128];    // h2 tile (swizzled, 16 chunks/row)
    __shared__ short sH[64 * 64];     // h3 tile (bf16, swizzled, 8 chunks/row)
    const int tid  = threadIdx.x;
    const int wv   = tid >> 6, lane = tid & 63;
    const int hi   = lane >> 4, lo = lane & 15;
    const int base = blockIdx.x * 64;

    {
        const float4* gv = reinterpret_cast<const float4*>(X1 + (size_t)base * 128);
        #pragma unroll
        for (int it = 0; it < 4; ++it) {
            int o = it * 256 + tid;
            int row = o >> 4, c = o & 15;
            float4 v = gv[row * 16 + c];
            *reinterpret_cast<float4*>(&sX[(row * 16 + (c ^ (row & 7))) * 8]) = v;
        }
    }
    __syncthreads();

    // stage 1: wave wv owns f-block wv (16 feats), all 64 nodes (4 A-strips)
    f32x4 acc[4];
    #pragma unroll
    for (int s = 0; s < 4; ++s) acc[s] = (f32x4){0.f, 0.f, 0.f, 0.f};
    #pragma unroll
    for (int kk = 0; kk < 4; ++kk) {
        bf16x8 w1 = *reinterpret_cast<const bf16x8*>(Wt1 + (size_t)(wv * 16 + lo) * 128 + kk * 32 + hi * 8);
        #pragma unroll
        for (int s = 0; s < 4; ++s) {
            int row = s * 16 + lo;
            int sw  = (kk * 4 + hi) ^ (row & 7);
            bf16x8 a = *reinterpret_cast<const bf16x8*>(&sX[(row * 16 + sw) * 8]);
            acc[s] = __builtin_amdgcn_mfma_f32_16x16x32_bf16(a, w1, acc[s], 0, 0, 0);
        }
    }

    // epilogue 1 -> sH (bf16, chunk-swizzled: c ^= row&7, 8 chunks/row)
    {
        int col = wv * 16 + lo;
        float bv = bias[col];
        #pragma unroll
        for (int s = 0; s < 4; ++s) {
            #pragma unroll
            for (int r = 0; r < 4; ++r) {
                int row  = s * 16 + hi * 4 + r;
                int node = base + row;
                float v = acc[s][r] + pre[(size_t)node * 64 + col] + bv;
                v = fmaxf(v, 0.0f);
                int c = (col >> 3) ^ (row & 7);
                sH[(row * 8 + c) * 8 + (col & 7)] = (short)f2b(v);
            }
        }
    }
    __syncthreads();

    // stage 2: out = h3 @ W4 + b4 ; wave wv owns A-strip wv (16 nodes), 3 f-blocks, K=64
    f32x4 acc2[3];
    #pragma unroll
    for (int fb = 0; fb < 3; ++fb) acc2[fb] = (f32x4){0.f, 0.f, 0.f, 0.f};
    #pragma unroll
    for (int kk = 0; kk < 2; ++kk) {
        int row = wv * 16 + lo;
        int sw  = (kk * 4 + hi) ^ (row & 7);
        bf16x8 a = *reinterpret_cast<const bf16x8*>(&sH[(row * 8 + sw) * 8]);
        #pragma unroll
        for (int fb = 0; fb < 3; ++fb) {
            bf16x8 w = *reinterpret_cast<const bf16x8*>(Wt4 + (size_t)(fb * 16 + lo) * 64 + kk * 32 + hi * 8);
            acc2[fb] = __builtin_amdgcn_mfma_f32_16x16x32_bf16(a, w, acc2[fb], 0, 0, 0);
        }
    }
    #pragma unroll
    for (int fb = 0; fb < 3; ++fb) {
        int f = fb * 16 + lo;
        if (f < 40) {
            float bv = b4[f];
            #pragma unroll
            for (int r = 0; r < 4; ++r) {
                int node = base + wv * 16 + hi * 4 + r;
                if (node < N_NODES)
                    out[(size_t)node * 40 + f] = acc2[fb][r] + bv;
            }
        }
    }
}

// ================= launch =================

extern "C" void kernel_launch(void* const* d_in, const int* in_sizes, int n_in,
                              void* d_out, int out_size, void* d_ws, size_t ws_size,
                              hipStream_t stream)
{
    const float* z   = (const float*)d_in[0];
    const int*   ei  = (const int*)d_in[1];
    const int*   src = ei;
    const int*   dst = ei + N_EDGES;
    const float* W1l = (const float*)d_in[2];
    const float* W1r = (const float*)d_in[3];
    const float* b1  = (const float*)d_in[4];
    const float* W2l = (const float*)d_in[5];
    const float* W2r = (const float*)d_in[6];
    const float* b2  = (const float*)d_in[7];
    const float* W3l = (const float*)d_in[8];
    const float* W3r = (const float*)d_in[9];
    const float* b3  = (const float*)d_in[10];
    const float* W4  = (const float*)d_in[11];
    const float* b4  = (const float*)d_in[12];
    float* out = (float*)d_out;

    // ---- workspace layout (all node arrays padded to N_PAD rows) ----
    ushort_t* h1b  = (ushort_t*)d_ws;                      // N_PAD*128 bf16
    ushort_t* aggb = h1b  + (size_t)N_PAD * 128;           // N_PAD*128 bf16
    ushort_t* h2b  = aggb + (size_t)N_PAD * 128;           // N_PAD*128 bf16
    ushort_t* t3b  = h2b  + (size_t)N_PAD * 128;           // N_PAD*64  bf16
    float* agg64   = (float*)(t3b + (size_t)N_PAD * 64);   // N_PAD*64  f32
    int2* rowbe    = (int2*)(agg64 + (size_t)N_PAD * 64);  // N ints x2
    int* csr       = (int*)(rowbe + N_NODES);              // NBUCK*BCAP ints
    uint_t* ebuf   = (uint_t*)(csr + (size_t)NBUCK * BCAP);// NBUCK*BCAP uints
    int* pcur      = (int*)(ebuf + (size_t)NBUCK * BCAP);  // NBUCK ints
    ushort_t* wt2l = (ushort_t*)(pcur + NBUCK);            // 128*128
    ushort_t* wt2r = wt2l + 128 * 128;
    ushort_t* wt3l = wt2r + 128 * 128;                     // 64*128
    ushort_t* wt3r = wt3l + 64 * 128;
    ushort_t* wt4  = wt3r + 64 * 128;                      // 48*64

    // ---- weight prep + pcur init (must precede k_bucket) ----
    k_prep_w<<<208, 256, 0, stream>>>(W2l, W2r, W3l, W3r, W4,
                                      wt2l, wt2r, wt3l, wt3r, wt4, pcur);

    // ---- CSR build (fixed-capacity buckets; no sizing pass) ----
    k_bucket<<<391, 256, 0, stream>>>(src, dst, pcur, ebuf, N_EDGES);
    k_build <<<NBUCK, 256, 0, stream>>>(ebuf, pcur, rowbe, csr);

    // ---- layer 1 (16 nodes per block) ----
    k_l1<<<(N_NODES + 15) / 16, 256, 0, stream>>>(rowbe, csr, z, W1l, W1r, b1, h1b, N_NODES);

    // ---- layer 2 ----
    k_gather128<<<(N_NODES + 15) / 16, 256, 0, stream>>>(rowbe, csr, h1b, aggb, N_NODES);
    k_mfma<128, true,  true,  true,  true ><<<NBLK, 256, 0, stream>>>(
        aggb, wt2l, h1b, wt2r, b2, h2b);

    // ---- layer 3 (pre-transform t3 = h2 @ W3l; mean is linear) ----
    k_mfma<64,  false, false, false, true ><<<NBLK, 256, 0, stream>>>(
        h2b, wt3l, nullptr, nullptr, nullptr, t3b);
    k_gather64<<<(N_NODES + 15) / 16, 256, 0, stream>>>(rowbe, csr, t3b, agg64, N_NODES);
    k_l3out<<<NBLK, 256, 0, stream>>>(h2b, wt3r, agg64, b3, wt4, b4, out);
}